// Round 5
// baseline (402.259 us; speedup 1.0000x reference)
//
#include <hip/hip_runtime.h>

// ---------------------------------------------------------------------------
// TernaryInvertedResidual on MI355X (gfx950) — R9
//
// vs R8 (267us total, fused conv2+3 = 137.4us): conv1 fused in as well ->
// ONE mega-kernel for conv1+conv2+conv3. Each 512-thread block (8 waves,
// launch_bounds(512,2) => 256-VGPR cap; R7's (512,4)=>128-cap spill disaster
// avoided) computes 4 output rows:
//   * x (6 input rows x 112 x 32ci) staged once to LDS as bf16 (43008 B).
//   * per cb seam: conv1 phase (84 MFMA over 8 waves, K=32 one-shot, BN +
//     ReLU6, swizzled ds_write) fills smA — replaces the HBM h1p round-trip
//     (conv1's 80 MB write + conv2's 110 MB fetch are GONE).
//   * conv2 main loop: same per-wave 96co x 112px tile, quad-buffered W,
//     counted vmcnt gates re-derived for 8-wave staging (4|2 / 2|1 / 0).
//   * conv3 epilogue: R8's scheme, 4 rows sequential through one P buffer.
// All MFMA K-orders identical to R8 -> bit-identical output.
// Also: stats_pass3 merged into pack_kernel (launch count 6 -> 4).
// LDS: xb 43008 | w1l 12288 | smA 43776 | smB 49152 | bn1 1536 = 149760 B.
// ---------------------------------------------------------------------------

typedef __bf16 bf16x8 __attribute__((ext_vector_type(8)));
typedef __bf16 bf16x4 __attribute__((ext_vector_type(4)));
typedef float  f32x4  __attribute__((ext_vector_type(4)));

#define EPSBN 1e-5f

#define XB_OFF   0        // 43008 B (union: P buffer in conv3 epilogue)
#define W1L_OFF  43008    // 12288 B (union: w3 in epilogue)
#define SMA_OFF  55296    // 43776 B (684 rows x 64B)
#define SMB_OFF  99072    // 49152 B (4 x 12288 quad-buffer)
#define SC1_OFF  148224   // 768 B
#define SH1_OFF  148992   // 768 B  -> total 149760

// async global->LDS, 16B per lane; LDS dest = wave-uniform base + lane*16
__device__ __forceinline__ void glds16(const void* g, void* l) {
  __builtin_amdgcn_global_load_lds(
      (const __attribute__((address_space(1))) void*)g,
      (__attribute__((address_space(3))) void*)l, 16, 0, 0);
}

__device__ __forceinline__ __bf16 tern(float w, float delta) {
  float aw = fabsf(w);
  float q = (aw > delta) ? ((w > 0.0f) ? 1.0f : -1.0f) : 0.0f;
  return (__bf16)q;
}

// ---------------- ternarize stats (deterministic, no atomics) --------------
// tensor index: 0=w1 (6144), 1=w2 (331776), 2=w3 (6144)

__global__ void stats_pass1(const float* __restrict__ w1, const float* __restrict__ w2,
                            const float* __restrict__ w3, double* __restrict__ pa) {
  __shared__ double red[256];
  int b = blockIdx.x, tid = threadIdx.x;
  int tix = b >> 5, slice = b & 31;
  const float* w = (tix == 0) ? w1 : (tix == 1) ? w2 : w3;
  int len = (tix == 1) ? 331776 : 6144;
  int per = len >> 5;
  int start = slice * per, end = start + per;
  double s = 0.0;
  for (int i = start + tid; i < end; i += 256) s += (double)fabsf(w[i]);
  red[tid] = s; __syncthreads();
  for (int off = 128; off > 0; off >>= 1) {
    if (tid < off) red[tid] += red[tid + off];
    __syncthreads();
  }
  if (tid == 0) pa[b] = red[0];
}

__global__ void stats_pass2(const float* __restrict__ w1, const float* __restrict__ w2,
                            const float* __restrict__ w3, const double* __restrict__ pa,
                            double* __restrict__ ps2, double* __restrict__ pc2) {
  __shared__ double red[256];
  int b = blockIdx.x, tid = threadIdx.x;
  int tix = b >> 5, slice = b & 31;
  const float* w = (tix == 0) ? w1 : (tix == 1) ? w2 : w3;
  int len = (tix == 1) ? 331776 : 6144;
  double tot = 0.0;
  for (int k = 0; k < 32; ++k) tot += pa[tix * 32 + k];
  float delta = 0.7f * (float)(tot / (double)len);
  int per = len >> 5;
  int start = slice * per, end = start + per;
  double s2 = 0.0, c2 = 0.0;
  for (int i = start + tid; i < end; i += 256) {
    float aw = fabsf(w[i]);
    if (aw > delta) { s2 += (double)aw; c2 += 1.0; }
  }
  red[tid] = s2; __syncthreads();
  for (int off = 128; off > 0; off >>= 1) {
    if (tid < off) red[tid] += red[tid + off];
    __syncthreads();
  }
  if (tid == 0) ps2[b] = red[0];
  __syncthreads();
  red[tid] = c2; __syncthreads();
  for (int off = 128; off > 0; off >>= 1) {
    if (tid < off) red[tid] += red[tid + off];
    __syncthreads();
  }
  if (tid == 0) pc2[b] = red[0];
}

// ---------------- weight pack + BN fold (+ final stats reduce) -------------
// w1p: [co=192][ci=32]  64B rows, 16B-chunk swizzled by ((co>>2)&3)
// w2p: [tap*6+cb][co=192][ci=32]  64B rows, 16B-chunk swizzled by ((co>>2)&3)
// w3p: [kc=3][co=32][ci=64]  128B rows, 16B-chunk swizzled by (co&7)
__global__ void pack_kernel(
    const float* __restrict__ w1, const float* __restrict__ w2, const float* __restrict__ w3,
    const float* __restrict__ g1, const float* __restrict__ b1, const float* __restrict__ m1, const float* __restrict__ v1,
    const float* __restrict__ g2, const float* __restrict__ b2, const float* __restrict__ m2, const float* __restrict__ v2,
    const float* __restrict__ g3, const float* __restrict__ b3, const float* __restrict__ m3, const float* __restrict__ v3,
    const double* __restrict__ pa, const double* __restrict__ ps2, const double* __restrict__ pc2,
    __bf16* __restrict__ w1p, __bf16* __restrict__ w2p, __bf16* __restrict__ w3p,
    float* __restrict__ sc1, float* __restrict__ sh1,
    float* __restrict__ sc2, float* __restrict__ sh2,
    float* __restrict__ sc3, float* __restrict__ sh3) {
  __shared__ float sst[6];
  int tid = threadIdx.x;
  if (tid < 3) {    // per-tensor final reduce (matches old stats_pass3 exactly)
    double tot = 0.0, s2 = 0.0, c2 = 0.0;
    for (int k = 0; k < 32; ++k) {
      tot += pa[tid * 32 + k];
      s2  += ps2[tid * 32 + k];
      c2  += pc2[tid * 32 + k];
    }
    int len = (tid == 1) ? 331776 : 6144;
    sst[tid * 2]     = 0.7f * (float)(tot / (double)len);  // delta
    sst[tid * 2 + 1] = (float)(s2 / fmax(c2, 1.0));        // alpha
  }
  __syncthreads();

  int idx = blockIdx.x * 256 + tid;
  if (idx < 331776) {
    float delta2 = sst[2];
    int c = idx / 6144, rem = idx - c * 6144;
    int co = rem >> 5, r5 = rem & 31;
    int cp = r5 >> 3, lo = r5 & 7;
    int tap = c / 6, cb = c - tap * 6;
    int ci = ((cp ^ ((co >> 2) & 3)) << 3) | lo;   // source-side chunk swizzle
    int cifull = cb * 32 + ci;
    w2p[idx] = tern(w2[(co * 192 + cifull) * 9 + tap], delta2);
    return;
  }
  idx -= 331776;
  if (idx < 6144) {  // w1p, swizzled
    int co = idx >> 5, c = (idx >> 3) & 3, lo = idx & 7;
    int ci = ((c ^ ((co >> 2) & 3)) << 3) | lo;
    w1p[idx] = tern(w1[co * 32 + ci], sst[0]);
    return;
  }
  idx -= 6144;
  if (idx < 6144) {  // w3p, swizzled
    int kc = idx >> 11, rem = idx & 2047;
    int co = rem >> 6, c = (rem >> 3) & 7, lo = rem & 7;
    int ci = ((c ^ (co & 7)) << 3) | lo;
    w3p[idx] = tern(w3[co * 192 + kc * 64 + ci], sst[4]);
    return;
  }
  idx -= 6144;
  if (idx < 192) {
    float rs = rsqrtf(v1[idx] + EPSBN);
    sc1[idx] = g1[idx] * rs * sst[1];
    sh1[idx] = b1[idx] - m1[idx] * g1[idx] * rs;
    return;
  }
  idx -= 192;
  if (idx < 192) {
    float rs = rsqrtf(v2[idx] + EPSBN);
    sc2[idx] = g2[idx] * rs * sst[3];
    sh2[idx] = b2[idx] - m2[idx] * g2[idx] * rs;
    return;
  }
  idx -= 192;
  if (idx < 32) {
    float rs = rsqrtf(v3[idx] + EPSBN);
    sc3[idx] = g3[idx] * rs * sst[5];
    sh3[idx] = b3[idx] - m3[idx] * g3[idx] * rs;
  }
}

// ---------------- fused conv1+conv2+conv3 ----------------------------------
// grid (28 h-quads, 16 n), 512 threads (8 waves: pg=wave>>1 row, cg=wave&1
// co-half). Per-wave conv2 tile: 96co x 112px, acc[7][6] — same as R8.

#define STAGE_W(TAP, CB, B) do {                                              \
  _Pragma("unroll")                                                           \
  for (int it_ = 0; it_ < 2; ++it_) {                                         \
    int t_ = wave + it_ * 8;                                                  \
    if (t_ < 12)                                                              \
      glds16(w2b + (long)((TAP) * 6 + (CB)) * 12288 + t_ * 1024 + lane * 16,  \
             smem + SMB_OFF + (B) * 12288 + t_ * 1024);                       \
  }                                                                           \
} while (0)

// conv1 for one cb: 84 MFMA over 8 waves (wave handles cf=cg, pf=pg+4k).
// reads xb + w1l + BN1 consts (all LDS), writes smA interior (swizzled).
#define CONV1_PHASE(CB) do {                                                  \
  int co0_ = (CB) * 32 + cg * 16 + quad * 4;                                  \
  float4 sc_ = *(const float4*)(smem + SC1_OFF + co0_ * 4);                   \
  float4 sh_ = *(const float4*)(smem + SH1_OFF + co0_ * 4);                   \
  bf16x8 aw1_ = *(const bf16x8*)(smem + W1L_OFF +                             \
                                 ((CB) * 32 + cg * 16 + mrow) * 64 + col16);  \
  _Pragma("unroll")                                                           \
  for (int k_ = 0; k_ < 11; ++k_) {                                           \
    int pf_ = pg + k_ * 4;                                                    \
    if (pf_ < 42) {                                                           \
      int r_ = pf_ / 7;                                                       \
      int xr_ = h0 - 1 + r_;                                                  \
      if (xr_ >= 0 && xr_ < 112) {                                            \
        bf16x8 bx_ = *(const bf16x8*)(smem + XB_OFF +                         \
                                      (pf_ * 16 + mrow) * 64 + col16);        \
        f32x4 a1_ = __builtin_amdgcn_mfma_f32_16x16x32_bf16(                  \
            aw1_, bx_, (f32x4)0.0f, 0, 0, 0);                                 \
        int wcol_ = (pf_ - r_ * 7) * 16 + mrow;                               \
        int srow_ = r_ * 114 + wcol_ + 1;                                     \
        bf16x4 o_;                                                            \
        o_[0] = (__bf16)fminf(fmaxf(a1_[0] * sc_.x + sh_.x, 0.0f), 6.0f);     \
        o_[1] = (__bf16)fminf(fmaxf(a1_[1] * sc_.y + sh_.y, 0.0f), 6.0f);     \
        o_[2] = (__bf16)fminf(fmaxf(a1_[2] * sc_.z + sh_.z, 0.0f), 6.0f);     \
        o_[3] = (__bf16)fminf(fmaxf(a1_[3] * sc_.w + sh_.w, 0.0f), 6.0f);     \
        int chk_ = ((cg * 2 + (quad >> 1)) ^ ((srow_ >> 2) & 3)) << 4;        \
        *(bf16x4*)(smem + SMA_OFF + srow_ * 64 + chk_ + (quad & 1) * 8) = o_; \
      }                                                                       \
    }                                                                         \
  }                                                                           \
} while (0)

__global__ __launch_bounds__(512, 2)
void fused_kernel(const float* __restrict__ x, const __bf16* __restrict__ w1p,
                  const float* __restrict__ sc1g, const float* __restrict__ sh1g,
                  const __bf16* __restrict__ w2p,
                  const float* __restrict__ scale2, const float* __restrict__ shift2,
                  const __bf16* __restrict__ w3p,
                  const float* __restrict__ scale3, const float* __restrict__ shift3,
                  float* __restrict__ out) {
  __shared__ __align__(16) char smem[149760];
  int tid = threadIdx.x, lane = tid & 63, wave = tid >> 6;
  int bh = blockIdx.x, n = blockIdx.y;
  int h0 = bh * 4;
  int pg = wave >> 1, cg = wave & 1;
  int mrow = lane & 15, quad = lane >> 4;
  int col16 = (quad ^ ((mrow >> 2) & 3)) * 16;
  const char* w2b = (const char*)w2p;

  // ---- one-time prologue ----
  // zero smA entirely (borders + out-of-range rows stay zero forever)
  for (int t = tid; t < 2736; t += 512)
    *(float4*)(smem + SMA_OFF + t * 16) = make_float4(0.f, 0.f, 0.f, 0.f);

  // stage w1p (12 KB) -> W1L
#pragma unroll
  for (int it = 0; it < 2; ++it) {
    int t = wave + it * 8;
    if (t < 12)
      glds16((const char*)w1p + t * 1024 + lane * 16, smem + W1L_OFF + t * 1024);
  }
  // stage BN1 consts -> LDS
  if (tid < 192) {
    *(float*)(smem + SC1_OFF + tid * 4) = sc1g[tid];
    *(float*)(smem + SH1_OFF + tid * 4) = sh1g[tid];
  }
  // stage x (6 rows h0-1..h0+4) as bf16, chunk-swizzled -> XB
  {
    const float* xn = x + (long)n * 401408;
    for (int i = 0; i < 11; ++i) {
      int f4 = i * 512 + tid;               // 0..5375 (float4 units)
      if (f4 < 5376) {
        int ci = f4 / 168, rem = f4 - ci * 168;
        int px0 = rem * 4;
        int r = px0 / 112, w0 = px0 - r * 112;
        int xr = h0 - 1 + r;
        if (xr >= 0 && xr < 112) {
          float4 v = *(const float4*)(xn + (ci * 112 + xr) * 112 + w0);
          int chunk = ((ci >> 3) ^ ((px0 >> 2) & 3)) << 4;
          char* base = smem + XB_OFF + px0 * 64 + chunk + (ci & 7) * 2;
          *(__bf16*)(base)       = (__bf16)v.x;
          *(__bf16*)(base + 64)  = (__bf16)v.y;
          *(__bf16*)(base + 128) = (__bf16)v.z;
          *(__bf16*)(base + 192) = (__bf16)v.w;
        }
      }
    }
  }
  asm volatile("s_waitcnt vmcnt(0) lgkmcnt(0)" ::: "memory");
  __builtin_amdgcn_s_barrier();
  __builtin_amdgcn_sched_barrier(0);

  f32x4 acc[7][6];
#pragma unroll
  for (int jp = 0; jp < 7; ++jp)
#pragma unroll
    for (int ic = 0; ic < 6; ++ic) acc[jp][ic] = (f32x4)0.0f;

  // prologue for cb=0: W prefetch in flight under the conv1 phase
  STAGE_W(0, 0, 0);
  STAGE_W(1, 0, 1);
  CONV1_PHASE(0);
  asm volatile("s_waitcnt lgkmcnt(0)" ::: "memory");
  __builtin_amdgcn_s_barrier();
  __builtin_amdgcn_sched_barrier(0);

  for (int cb = 0; cb < 6; ++cb) {
#pragma unroll
    for (int tap = 0; tap < 9; ++tap) {
      if (tap <= 6) {
        STAGE_W(tap + 2, cb, (tap + 2) & 3);
        // retire W(tap); keep W(tap+1),W(tap+2) in flight (2|1 loads per buf)
        if (wave < 4) asm volatile("s_waitcnt vmcnt(4)" ::: "memory");
        else          asm volatile("s_waitcnt vmcnt(2)" ::: "memory");
      } else if (tap == 7) {
        if (wave < 4) asm volatile("s_waitcnt vmcnt(2)" ::: "memory");
        else          asm volatile("s_waitcnt vmcnt(1)" ::: "memory");
      } else {
        asm volatile("s_waitcnt vmcnt(0)" ::: "memory");
      }
      __builtin_amdgcn_s_barrier();
      __builtin_amdgcn_sched_barrier(0);

      const char* bbuf = smem + SMB_OFF + (tap & 3) * 12288;
      bf16x8 aw[6];
#pragma unroll
      for (int ic = 0; ic < 6; ++ic)
        aw[ic] = *(const bf16x8*)(bbuf + (cg * 96 + ic * 16 + mrow) * 64 + col16);

      int dy = tap / 3, dx = tap - dy * 3;
      int base = (pg + dy) * 114 + dx;
      __builtin_amdgcn_s_setprio(1);
#pragma unroll
      for (int jp = 0; jp < 7; ++jp) {
        int row = base + jp * 16 + mrow;
        bf16x8 av = *(const bf16x8*)(smem + SMA_OFF + row * 64 +
                                     ((quad ^ ((row >> 2) & 3)) * 16));
#pragma unroll
        for (int ic = 0; ic < 6; ++ic)
          acc[jp][ic] = __builtin_amdgcn_mfma_f32_16x16x32_bf16(aw[ic], av, acc[jp][ic], 0, 0, 0);
      }
      __builtin_amdgcn_s_setprio(0);
    }

    // seam: drain smA reads, then conv1-compute next cb's smA (+W prefetch)
    if (cb < 5) {
      asm volatile("s_waitcnt lgkmcnt(0)" ::: "memory");
      __builtin_amdgcn_sched_barrier(0);
      __builtin_amdgcn_s_barrier();
      STAGE_W(0, cb + 1, 0);
      STAGE_W(1, cb + 1, 1);
      CONV1_PHASE(cb + 1);
      asm volatile("s_waitcnt lgkmcnt(0)" ::: "memory");
      __builtin_amdgcn_s_barrier();
      __builtin_amdgcn_sched_barrier(0);
    }
  }

  // ---------------- fused conv3 epilogue (4 rows) --------------------------
  asm volatile("s_waitcnt lgkmcnt(0)" ::: "memory");
  __builtin_amdgcn_s_barrier();
  __builtin_amdgcn_sched_barrier(0);

  // stage w3 (12288 B) into W1L region (now dead)
#pragma unroll
  for (int it = 0; it < 2; ++it) {
    int t = wave + it * 8;
    if (t < 12)
      glds16((const char*)w3p + t * 1024 + lane * 16, smem + W1L_OFF + t * 1024);
  }

  int co3 = cg * 16 + mrow;
  float sc3v = scale3[co3], sh3v = shift3[co3];

#pragma unroll
  for (int rg = 0; rg < 4; ++rg) {
    if (pg == rg) {
      // write this wave's co-half of P-row rg (BN + ReLU6, bf16, swizzled)
#pragma unroll
      for (int ic = 0; ic < 6; ++ic) {
        int co0 = cg * 96 + ic * 16 + quad * 4;
        float4 sc = *(const float4*)(scale2 + co0);
        float4 sh = *(const float4*)(shift2 + co0);
        int kc = co0 >> 6, c6 = co0 & 63;
        int chunk = c6 >> 3, off = c6 & 7;
#pragma unroll
        for (int jp = 0; jp < 7; ++jp) {
          int px = jp * 16 + mrow;
          bf16x4 o;
          o[0] = (__bf16)fminf(fmaxf(acc[jp][ic][0] * sc.x + sh.x, 0.0f), 6.0f);
          o[1] = (__bf16)fminf(fmaxf(acc[jp][ic][1] * sc.y + sh.y, 0.0f), 6.0f);
          o[2] = (__bf16)fminf(fmaxf(acc[jp][ic][2] * sc.z + sh.z, 0.0f), 6.0f);
          o[3] = (__bf16)fminf(fmaxf(acc[jp][ic][3] * sc.w + sh.w, 0.0f), 6.0f);
          *(bf16x4*)(smem + XB_OFF + px * 384 + kc * 128 +
                     ((chunk ^ (px & 7)) * 16) + off * 2) = o;
        }
      }
    }
    if (rg == 0)
      asm volatile("s_waitcnt vmcnt(0) lgkmcnt(0)" ::: "memory");
    else
      asm volatile("s_waitcnt lgkmcnt(0)" ::: "memory");
    __builtin_amdgcn_s_barrier();
    __builtin_amdgcn_sched_barrier(0);

    // conv3 on row rg: wave covers co3 (cg half) x px frags {2*pg, 2*pg+1}
    f32x4 acc3[2];
    acc3[0] = (f32x4)0.0f; acc3[1] = (f32x4)0.0f;
    int swz = mrow & 7;
#pragma unroll
    for (int kc = 0; kc < 3; ++kc) {
      bf16x8 b0 = *(const bf16x8*)(smem + W1L_OFF + kc * 4096 +
                                   (cg * 16 + mrow) * 128 + ((quad ^ swz) * 16));
      bf16x8 b1 = *(const bf16x8*)(smem + W1L_OFF + kc * 4096 +
                                   (cg * 16 + mrow) * 128 + (((4 + quad) ^ swz) * 16));
#pragma unroll
      for (int f2 = 0; f2 < 2; ++f2) {
        int f = pg * 2 + f2;
        if (f < 7) {
          int pr = f * 16 + mrow;
          bf16x8 a0 = *(const bf16x8*)(smem + XB_OFF + pr * 384 + kc * 128 +
                                       ((quad ^ swz) * 16));
          bf16x8 a1 = *(const bf16x8*)(smem + XB_OFF + pr * 384 + kc * 128 +
                                       (((4 + quad) ^ swz) * 16));
          acc3[f2] = __builtin_amdgcn_mfma_f32_16x16x32_bf16(a0, b0, acc3[f2], 0, 0, 0);
          acc3[f2] = __builtin_amdgcn_mfma_f32_16x16x32_bf16(a1, b1, acc3[f2], 0, 0, 0);
        }
      }
    }
    // BN (no act) + residual, fp32 float4 stores to NCHW
    int h = h0 + rg;
    long obase = ((long)(n * 32 + co3) * 112 + h) * 112;
    const float* xb = x + obase;
    float* ob = out + obase;
#pragma unroll
    for (int f2 = 0; f2 < 2; ++f2) {
      int f = pg * 2 + f2;
      if (f < 7) {
        int w0 = f * 16 + quad * 4;
        float4 xv = *(const float4*)(xb + w0);
        float4 o;
        o.x = acc3[f2][0] * sc3v + sh3v + xv.x;
        o.y = acc3[f2][1] * sc3v + sh3v + xv.y;
        o.z = acc3[f2][2] * sc3v + sh3v + xv.z;
        o.w = acc3[f2][3] * sc3v + sh3v + xv.w;
        *(float4*)(ob + w0) = o;
      }
    }
    if (rg < 3) {   // P-buffer reads done before next row overwrites it
      asm volatile("s_waitcnt lgkmcnt(0)" ::: "memory");
      __builtin_amdgcn_s_barrier();
      __builtin_amdgcn_sched_barrier(0);
    }
  }
}

// ---------------- launch ---------------------------------------------------
extern "C" void kernel_launch(void* const* d_in, const int* in_sizes, int n_in,
                              void* d_out, int out_size, void* d_ws, size_t ws_size,
                              hipStream_t stream) {
  const float* x  = (const float*)d_in[0];
  const float* w1 = (const float*)d_in[1];
  const float* g1 = (const float*)d_in[2];
  const float* b1 = (const float*)d_in[3];
  const float* m1 = (const float*)d_in[4];
  const float* v1 = (const float*)d_in[5];
  const float* w2 = (const float*)d_in[6];
  const float* g2 = (const float*)d_in[7];
  const float* b2 = (const float*)d_in[8];
  const float* m2 = (const float*)d_in[9];
  const float* v2 = (const float*)d_in[10];
  const float* w3 = (const float*)d_in[11];
  const float* g3 = (const float*)d_in[12];
  const float* b3 = (const float*)d_in[13];
  const float* m3 = (const float*)d_in[14];
  const float* v3 = (const float*)d_in[15];
  float* out = (float*)d_out;

  char* ws = (char*)d_ws;
  double* pa    = (double*)(ws + 256);        // 96 doubles
  double* ps2   = (double*)(ws + 1024);
  double* pc2   = (double*)(ws + 1792);
  float* sc1 = (float*)(ws + 2560);
  float* sh1 = (float*)(ws + 3328);
  float* sc2 = (float*)(ws + 4096);
  float* sh2 = (float*)(ws + 4864);
  float* sc3 = (float*)(ws + 5632);
  float* sh3 = (float*)(ws + 5760);
  __bf16* w1p = (__bf16*)(ws + 8192);         // 12288 B
  __bf16* w3p = (__bf16*)(ws + 20480);        // 12288 B
  __bf16* w2p = (__bf16*)(ws + 32768);        // 663552 B

  hipLaunchKernelGGL(stats_pass1, dim3(96), dim3(256), 0, stream, w1, w2, w3, pa);
  hipLaunchKernelGGL(stats_pass2, dim3(96), dim3(256), 0, stream, w1, w2, w3, pa, ps2, pc2);
  hipLaunchKernelGGL(pack_kernel, dim3(1346), dim3(256), 0, stream, w1, w2, w3,
                     g1, b1, m1, v1, g2, b2, m2, v2, g3, b3, m3, v3, pa, ps2, pc2,
                     w1p, w2p, w3p, sc1, sh1, sc2, sh2, sc3, sh3);
  hipLaunchKernelGGL(fused_kernel, dim3(28, 16), dim3(512), 0, stream, x, w1p, sc1, sh1,
                     w2p, sc2, sh2, w3p, sc3, sh3, out);
}

// Round 6
// 261.414 us; speedup vs baseline: 1.5388x; 1.5388x over previous
//
#include <hip/hip_runtime.h>

// ---------------------------------------------------------------------------
// TernaryInvertedResidual on MI355X (gfx950) — R10
//
// vs R9 (FAILED: conv1-in-seam spilled the 168-reg conv2 accumulator ->
// 190 MB scratch traffic, 311us): mega-fusion reverted. Base = R8 (verified
// 267us total, fused conv2+3 = 137.4us, byte-identical here). Changes:
//   * stats_pass3 merged into pack_kernel (R9-verified path): 6 -> 5 launches.
//   * conv1 v2: (a) x staging vectorized — float4 loads + bf16x4 ds_writes
//     (4x fewer LDS writes, 4x fewer load instrs); (b) epilogue restaged
//     through a swizzled LDS P buffer (112 rows x 512 B padded, chunk XOR
//     (w&31)) then stored as fully-coalesced float4 over the contiguous
//     43008 B interior row — replaces 21 scattered 8 B global stores/thread.
//     Same values, same destinations -> identical output.
// ---------------------------------------------------------------------------

typedef __bf16 bf16x8 __attribute__((ext_vector_type(8)));
typedef __bf16 bf16x4 __attribute__((ext_vector_type(4)));
typedef float  f32x4  __attribute__((ext_vector_type(4)));

#define EPSBN 1e-5f

// async global->LDS, 16B per lane; LDS dest = wave-uniform base + lane*16
__device__ __forceinline__ void glds16(const void* g, void* l) {
  __builtin_amdgcn_global_load_lds(
      (const __attribute__((address_space(1))) void*)g,
      (__attribute__((address_space(3))) void*)l, 16, 0, 0);
}

__device__ __forceinline__ __bf16 tern(float w, float delta) {
  float aw = fabsf(w);
  float q = (aw > delta) ? ((w > 0.0f) ? 1.0f : -1.0f) : 0.0f;
  return (__bf16)q;
}

// ---------------- ternarize stats (deterministic, no atomics) --------------
// tensor index: 0=w1 (6144), 1=w2 (331776), 2=w3 (6144)

__global__ void stats_pass1(const float* __restrict__ w1, const float* __restrict__ w2,
                            const float* __restrict__ w3, double* __restrict__ pa) {
  __shared__ double red[256];
  int b = blockIdx.x, tid = threadIdx.x;
  int tix = b >> 5, slice = b & 31;
  const float* w = (tix == 0) ? w1 : (tix == 1) ? w2 : w3;
  int len = (tix == 1) ? 331776 : 6144;
  int per = len >> 5;
  int start = slice * per, end = start + per;
  double s = 0.0;
  for (int i = start + tid; i < end; i += 256) s += (double)fabsf(w[i]);
  red[tid] = s; __syncthreads();
  for (int off = 128; off > 0; off >>= 1) {
    if (tid < off) red[tid] += red[tid + off];
    __syncthreads();
  }
  if (tid == 0) pa[b] = red[0];
}

__global__ void stats_pass2(const float* __restrict__ w1, const float* __restrict__ w2,
                            const float* __restrict__ w3, const double* __restrict__ pa,
                            double* __restrict__ ps2, double* __restrict__ pc2) {
  __shared__ double red[256];
  int b = blockIdx.x, tid = threadIdx.x;
  int tix = b >> 5, slice = b & 31;
  const float* w = (tix == 0) ? w1 : (tix == 1) ? w2 : w3;
  int len = (tix == 1) ? 331776 : 6144;
  double tot = 0.0;
  for (int k = 0; k < 32; ++k) tot += pa[tix * 32 + k];
  float delta = 0.7f * (float)(tot / (double)len);
  int per = len >> 5;
  int start = slice * per, end = start + per;
  double s2 = 0.0, c2 = 0.0;
  for (int i = start + tid; i < end; i += 256) {
    float aw = fabsf(w[i]);
    if (aw > delta) { s2 += (double)aw; c2 += 1.0; }
  }
  red[tid] = s2; __syncthreads();
  for (int off = 128; off > 0; off >>= 1) {
    if (tid < off) red[tid] += red[tid + off];
    __syncthreads();
  }
  if (tid == 0) ps2[b] = red[0];
  __syncthreads();
  red[tid] = c2; __syncthreads();
  for (int off = 128; off > 0; off >>= 1) {
    if (tid < off) red[tid] += red[tid + off];
    __syncthreads();
  }
  if (tid == 0) pc2[b] = red[0];
}

// ---------------- weight pack + BN fold (+ final stats reduce) -------------
// w1p: [co=192][ci=32]  64B rows, 16B-chunk swizzled by ((co>>2)&3)
// w2p: [tap*6+cb][co=192][ci=32]  64B rows, 16B-chunk swizzled by ((co>>2)&3)
// w3p: [kc=3][co=32][ci=64]  128B rows, 16B-chunk swizzled by (co&7)
__global__ void pack_kernel(
    const float* __restrict__ w1, const float* __restrict__ w2, const float* __restrict__ w3,
    const float* __restrict__ g1, const float* __restrict__ b1, const float* __restrict__ m1, const float* __restrict__ v1,
    const float* __restrict__ g2, const float* __restrict__ b2, const float* __restrict__ m2, const float* __restrict__ v2,
    const float* __restrict__ g3, const float* __restrict__ b3, const float* __restrict__ m3, const float* __restrict__ v3,
    const double* __restrict__ pa, const double* __restrict__ ps2, const double* __restrict__ pc2,
    __bf16* __restrict__ w1p, __bf16* __restrict__ w2p, __bf16* __restrict__ w3p,
    float* __restrict__ sc1, float* __restrict__ sh1,
    float* __restrict__ sc2, float* __restrict__ sh2,
    float* __restrict__ sc3, float* __restrict__ sh3) {
  __shared__ float sst[6];
  int tid = threadIdx.x;
  if (tid < 3) {    // per-tensor final reduce (matches old stats_pass3 exactly)
    double tot = 0.0, s2 = 0.0, c2 = 0.0;
    for (int k = 0; k < 32; ++k) {
      tot += pa[tid * 32 + k];
      s2  += ps2[tid * 32 + k];
      c2  += pc2[tid * 32 + k];
    }
    int len = (tid == 1) ? 331776 : 6144;
    sst[tid * 2]     = 0.7f * (float)(tot / (double)len);  // delta
    sst[tid * 2 + 1] = (float)(s2 / fmax(c2, 1.0));        // alpha
  }
  __syncthreads();

  int idx = blockIdx.x * 256 + tid;
  if (idx < 331776) {
    float delta2 = sst[2];
    int c = idx / 6144, rem = idx - c * 6144;
    int co = rem >> 5, r5 = rem & 31;
    int cp = r5 >> 3, lo = r5 & 7;
    int tap = c / 6, cb = c - tap * 6;
    int ci = ((cp ^ ((co >> 2) & 3)) << 3) | lo;   // source-side chunk swizzle
    int cifull = cb * 32 + ci;
    w2p[idx] = tern(w2[(co * 192 + cifull) * 9 + tap], delta2);
    return;
  }
  idx -= 331776;
  if (idx < 6144) {  // w1p, swizzled
    int co = idx >> 5, c = (idx >> 3) & 3, lo = idx & 7;
    int ci = ((c ^ ((co >> 2) & 3)) << 3) | lo;
    w1p[idx] = tern(w1[co * 32 + ci], sst[0]);
    return;
  }
  idx -= 6144;
  if (idx < 6144) {  // w3p, swizzled
    int kc = idx >> 11, rem = idx & 2047;
    int co = rem >> 6, c = (rem >> 3) & 7, lo = rem & 7;
    int ci = ((c ^ (co & 7)) << 3) | lo;
    w3p[idx] = tern(w3[co * 192 + kc * 64 + ci], sst[4]);
    return;
  }
  idx -= 6144;
  if (idx < 192) {
    float rs = rsqrtf(v1[idx] + EPSBN);
    sc1[idx] = g1[idx] * rs * sst[1];
    sh1[idx] = b1[idx] - m1[idx] * g1[idx] * rs;
    return;
  }
  idx -= 192;
  if (idx < 192) {
    float rs = rsqrtf(v2[idx] + EPSBN);
    sc2[idx] = g2[idx] * rs * sst[3];
    sh2[idx] = b2[idx] - m2[idx] * g2[idx] * rs;
    return;
  }
  idx -= 192;
  if (idx < 32) {
    float rs = rsqrtf(v3[idx] + EPSBN);
    sc3[idx] = g3[idx] * rs * sst[5];
    sh3[idx] = b3[idx] - m3[idx] * g3[idx] * rs;
  }
}

// ---------------- conv1 v2: 1x1 (K=32) + fused border zero -----------------
// grid (112 h, 16 n), 256 threads (4 waves). A=weights (M=co 192), B=acts
// (N=w 112). Wave co-range 48 (3 frags) x 112 px (7 frags).
// v2: float4 x staging; epilogue via swizzled LDS P buffer -> coalesced
// float4 global stores over the contiguous 43008 B interior row.
__global__ __launch_bounds__(256)
void conv1_kernel(const float* __restrict__ x, const __bf16* __restrict__ w1p,
                  const float* __restrict__ scale1, const float* __restrict__ shift1,
                  __bf16* __restrict__ h1p) {
  __shared__ __align__(16) char smem[57344];
  char* smA = smem;          // 7168 B acts [w][ci32] 64B rows, chunk-swizzled
  char* smB = smem + 7168;   // 12288 B weights (swizzle baked in w1p)
  char* Pb  = smem;          // 57344 B epilogue union: 112 rows x 512 B
  int tid = threadIdx.x, lane = tid & 63, wave = tid >> 6;
  int h = blockIdx.x, n = blockIdx.y;

  for (int t = wave; t < 12; t += 4)
    glds16((const char*)w1p + t * 1024 + lane * 16, smB + t * 1024);

  // x staging: group g -> ci0=(g/112)*4, w=g%112; 4 coalesced loads, 1 b64 write
  const float* xrow = x + (long)n * 401408 + h * 112;   // + ci*12544 + w
#pragma unroll
  for (int i = 0; i < 4; ++i) {
    int g = i * 256 + tid;
    if (g < 896) {
      int ci0 = (g / 112) * 4, w = g - (g / 112) * 112;
      const float* p = xrow + ci0 * 12544 + w;
      bf16x4 v;
      v[0] = (__bf16)p[0];
      v[1] = (__bf16)p[12544];
      v[2] = (__bf16)p[25088];
      v[3] = (__bf16)p[37632];
      int col = ((ci0 >> 3) ^ ((w >> 2) & 3));
      *(bf16x4*)(smA + w * 64 + (col << 4) + (ci0 & 7) * 2) = v;
    }
  }
  __syncthreads();

  int mrow = lane & 15, quad = lane >> 4;
  int col16 = (quad ^ ((mrow >> 2) & 3)) * 16;
  int c0 = wave * 48;

  bf16x8 aw[3], bv[7];
#pragma unroll
  for (int ic = 0; ic < 3; ++ic)
    aw[ic] = *(const bf16x8*)(smB + (c0 + ic * 16 + mrow) * 64 + col16);
#pragma unroll
  for (int jp = 0; jp < 7; ++jp)
    bv[jp] = *(const bf16x8*)(smA + (jp * 16 + mrow) * 64 + col16);

  // frags now in flight; drain + fence before LDS is reused as P buffer
  asm volatile("s_waitcnt lgkmcnt(0)" ::: "memory");
  __builtin_amdgcn_s_barrier();
  __builtin_amdgcn_sched_barrier(0);

  f32x4 acc[7][3];
#pragma unroll
  for (int jp = 0; jp < 7; ++jp)
#pragma unroll
    for (int ic = 0; ic < 3; ++ic) acc[jp][ic] = (f32x4)0.0f;

#pragma unroll
  for (int jp = 0; jp < 7; ++jp)
#pragma unroll
    for (int ic = 0; ic < 3; ++ic)
      acc[jp][ic] = __builtin_amdgcn_mfma_f32_16x16x32_bf16(aw[ic], bv[jp], acc[jp][ic], 0, 0, 0);

  // epilogue: BN + ReLU6 -> P LDS (padded 512B rows, chunk XOR (w&31))
#pragma unroll
  for (int ic = 0; ic < 3; ++ic) {
    int co0 = c0 + ic * 16 + quad * 4;
    float4 sc = *(const float4*)(scale1 + co0);
    float4 sh = *(const float4*)(shift1 + co0);
    int lch = co0 >> 3;                 // 6*wave + 2*ic + (quad>>1)
    int boff = (quad & 1) * 8;          // (co0&7)*2
#pragma unroll
    for (int jp = 0; jp < 7; ++jp) {
      int w = jp * 16 + mrow;
      bf16x4 o;
      o[0] = (__bf16)fminf(fmaxf(acc[jp][ic][0] * sc.x + sh.x, 0.0f), 6.0f);
      o[1] = (__bf16)fminf(fmaxf(acc[jp][ic][1] * sc.y + sh.y, 0.0f), 6.0f);
      o[2] = (__bf16)fminf(fmaxf(acc[jp][ic][2] * sc.z + sh.z, 0.0f), 6.0f);
      o[3] = (__bf16)fminf(fmaxf(acc[jp][ic][3] * sc.w + sh.w, 0.0f), 6.0f);
      *(bf16x4*)(Pb + w * 512 + ((lch ^ (w & 31)) << 4) + boff) = o;
    }
  }
  asm volatile("s_waitcnt lgkmcnt(0)" ::: "memory");
  __builtin_amdgcn_s_barrier();
  __builtin_amdgcn_sched_barrier(0);

  // coalesced copy-out: interior row = contiguous 2688 x 16B
  __bf16* obase = h1p + ((long)(n * 114 + h + 1) * 114 + 1) * 192;
#pragma unroll
  for (int i = 0; i < 11; ++i) {
    int c = i * 256 + tid;
    if (c < 2688) {
      int w = c / 24, lch = c - w * 24;
      float4 v = *(const float4*)(Pb + w * 512 + ((lch ^ (w & 31)) << 4));
      *(float4*)((char*)obase + c * 16) = v;
    }
  }

  // fused border zeroing of h1p
  float4 z = make_float4(0.f, 0.f, 0.f, 0.f);
  if (tid < 48) {
    int px = (tid < 24) ? 0 : 113;
    int c8 = (tid < 24) ? tid : tid - 24;
    *(float4*)((char*)h1p + ((long)((n * 114 + h + 1) * 114 + px) * 384) + c8 * 16) = z;
  }
  if (h == 0) {
    for (int c = tid; c < 2736; c += 256)
      *(float4*)((char*)h1p + (long)(n * 114) * 114 * 384 + c * 16) = z;
  }
  if (h == 111) {
    for (int c = tid; c < 2736; c += 256)
      *(float4*)((char*)h1p + (long)(n * 114 + 113) * 114 * 384 + c * 16) = z;
  }
}

// ---------------- conv2+conv3 fused (byte-identical to R8) -----------------
// grid (56 h-pairs, 16 n), 256 threads (4 waves).
// Main loop: quad-buffered weights, counted vmcnt gates.
// Epilogue: P-rows (BN+ReLU6 bf16) -> LDS, w3 staged to LDS, conv3's exact
// MFMA sequence (kc0ks0..kc2ks1) + BN + residual -> out (fp32 NCHW).
// LDS union (78336 B): main {smA 29184 | smB 4x12288} / epi {P 43008 | w3 12288}

#define STAGE_W(TAP, CB, B) do {                                              \
  _Pragma("unroll")                                                           \
  for (int it_ = 0; it_ < 3; ++it_) {                                         \
    int t_ = wave + it_ * 4;                                                  \
    glds16(w2b + (long)((TAP) * 6 + (CB)) * 12288 + t_ * 1024 + lane * 16,    \
           smBb + (B) * 12288 + t_ * 1024);                                   \
  }                                                                           \
} while (0)

#define STAGE_A(CB) do {                                                      \
  _Pragma("unroll")                                                           \
  for (int it_ = 0; it_ < 8; ++it_)                                           \
    if (aoff[it_] >= 0)                                                       \
      glds16(h1b + aoff[it_] + (CB) * 64, smAb + (wave + it_ * 4) * 1024);    \
} while (0)

__global__ __launch_bounds__(256, 2)
void conv2_kernel(const __bf16* __restrict__ h1p, const __bf16* __restrict__ w2p,
                  const float* __restrict__ scale2, const float* __restrict__ shift2,
                  const __bf16* __restrict__ w3p,
                  const float* __restrict__ scale3, const float* __restrict__ shift3,
                  const float* __restrict__ x, float* __restrict__ out) {
  __shared__ __align__(16) char smem[78336];
  char* smAb = smem;            // 29184 B act window (main loop)
  char* smBb = smem + 29184;    // 4 x 12288 B weights (main loop)
  char* Pb   = smem;            // 43008 B P-row (epilogue)
  char* w3l  = smem + 43008;    // 12288 B w3 (epilogue)
  int tid = threadIdx.x, lane = tid & 63, wave = tid >> 6;
  int bh = blockIdx.x, n = blockIdx.y;
  int h0 = bh * 2;

  // A staging source offsets (bytes, + cb*64 at use); slot s = t*64+lane
  int aoff[8];
#pragma unroll
  for (int it = 0; it < 8; ++it) {
    int t = wave + it * 4;
    int s = t * 64 + lane;
    if (s < 1824) {
      int q = s >> 2, c = s & 3;
      int q_log = c ^ ((q >> 2) & 3);
      int prow = q / 114, pcol = q - prow * 114;
      aoff[it] = ((n * 114 + h0 + prow) * 114 + pcol) * 384 + q_log * 16;
    } else {
      aoff[it] = -1;
    }
  }

  int pg = wave >> 1, cg = wave & 1;
  int mrow = lane & 15, quad = lane >> 4;
  int col16 = (quad ^ ((mrow >> 2) & 3)) * 16;
  const char* h1b = (const char*)h1p;
  const char* w2b = (const char*)w2p;

  f32x4 acc[7][6];
#pragma unroll
  for (int jp = 0; jp < 7; ++jp)
#pragma unroll
    for (int ic = 0; ic < 6; ++ic) acc[jp][ic] = (f32x4)0.0f;

  // prologue: A(0) + W0->buf0 + W1->buf1 in flight before the first gate
  STAGE_A(0);
  STAGE_W(0, 0, 0);
  STAGE_W(1, 0, 1);

  for (int cb = 0; cb < 6; ++cb) {
#pragma unroll
    for (int tap = 0; tap < 9; ++tap) {
      if (tap <= 6) {
        STAGE_W(tap + 2, cb, (tap + 2) & 3);
        asm volatile("s_waitcnt vmcnt(6)" ::: "memory");   // W(tap) + A done
      } else if (tap == 7) {
        asm volatile("s_waitcnt vmcnt(3)" ::: "memory");   // W(7) done
      } else {
        asm volatile("s_waitcnt vmcnt(0)" ::: "memory");   // W(8) done
      }
      __builtin_amdgcn_s_barrier();
      __builtin_amdgcn_sched_barrier(0);

      const char* bbuf = smBb + (tap & 3) * 12288;
      bf16x8 aw[6];
#pragma unroll
      for (int ic = 0; ic < 6; ++ic)
        aw[ic] = *(const bf16x8*)(bbuf + (cg * 96 + ic * 16 + mrow) * 64 + col16);

      int dy = tap / 3, dx = tap - dy * 3;
      int base = (pg + dy) * 114 + dx;
      __builtin_amdgcn_s_setprio(1);
#pragma unroll
      for (int jp = 0; jp < 7; ++jp) {
        int row = base + jp * 16 + mrow;
        bf16x8 av = *(const bf16x8*)(smAb + row * 64 +
                                     ((quad ^ ((row >> 2) & 3)) * 16));
#pragma unroll
        for (int ic = 0; ic < 6; ++ic)
          acc[jp][ic] = __builtin_amdgcn_mfma_f32_16x16x32_bf16(aw[ic], av, acc[jp][ic], 0, 0, 0);
      }
      __builtin_amdgcn_s_setprio(0);
    }

    // once per cb: drain LDS reads, fence all waves, prestage next cb
    if (cb < 5) {
      asm volatile("s_waitcnt lgkmcnt(0)" ::: "memory");
      __builtin_amdgcn_sched_barrier(0);
      __builtin_amdgcn_s_barrier();
      STAGE_A(cb + 1);
      STAGE_W(0, cb + 1, 0);
      STAGE_W(1, cb + 1, 1);
    }
  }

  // ---------------- fused conv3 epilogue ----------------------------------
  asm volatile("s_waitcnt lgkmcnt(0)" ::: "memory");
  __builtin_amdgcn_s_barrier();
  __builtin_amdgcn_sched_barrier(0);

  // stage w3 (12288 B) into w3l
#pragma unroll
  for (int it = 0; it < 3; ++it) {
    int t = wave + it * 4;
    glds16((const char*)w3p + t * 1024 + lane * 16, w3l + t * 1024);
  }

  // per-lane conv3 BN params: co = (wave&1)*16 + mrow
  int cohalf = wave & 1;
  int co3 = cohalf * 16 + mrow;
  float sc3v = scale3[co3], sh3v = shift3[co3];
  int fbase = (wave >> 1) * 4;             // waves 0,1 -> frags 0..3; 2,3 -> 4..6

#pragma unroll
  for (int rg = 0; rg < 2; ++rg) {
    if (pg == rg) {
      // write this wave's half (cg) of P-row rg
#pragma unroll
      for (int ic = 0; ic < 6; ++ic) {
        int co0 = cg * 96 + ic * 16 + quad * 4;
        float4 sc = *(const float4*)(scale2 + co0);
        float4 sh = *(const float4*)(shift2 + co0);
        int kc = co0 >> 6, c6 = co0 & 63;
        int chunk = c6 >> 3, off = c6 & 7;
#pragma unroll
        for (int jp = 0; jp < 7; ++jp) {
          int px = jp * 16 + mrow;
          bf16x4 o;
          o[0] = (__bf16)fminf(fmaxf(acc[jp][ic][0] * sc.x + sh.x, 0.0f), 6.0f);
          o[1] = (__bf16)fminf(fmaxf(acc[jp][ic][1] * sc.y + sh.y, 0.0f), 6.0f);
          o[2] = (__bf16)fminf(fmaxf(acc[jp][ic][2] * sc.z + sh.z, 0.0f), 6.0f);
          o[3] = (__bf16)fminf(fmaxf(acc[jp][ic][3] * sc.w + sh.w, 0.0f), 6.0f);
          *(bf16x4*)(Pb + px * 384 + kc * 128 + ((chunk ^ (px & 7)) * 16) + off * 2) = o;
        }
      }
    }
    // P writes + (rg==0: w3 stage) must land before reads
    if (rg == 0)
      asm volatile("s_waitcnt vmcnt(0) lgkmcnt(0)" ::: "memory");
    else
      asm volatile("s_waitcnt lgkmcnt(0)" ::: "memory");
    __builtin_amdgcn_s_barrier();
    __builtin_amdgcn_sched_barrier(0);

    // conv3 on row rg: wave covers co 16*(wave&1).. and px frags fbase..(+3|+2)
    f32x4 acc3[4];
#pragma unroll
    for (int f = 0; f < 4; ++f) acc3[f] = (f32x4)0.0f;
    int swz = mrow & 7;
#pragma unroll
    for (int kc = 0; kc < 3; ++kc) {
      bf16x8 b0 = *(const bf16x8*)(w3l + kc * 4096 + (cohalf * 16 + mrow) * 128 +
                                   ((quad ^ swz) * 16));
      bf16x8 b1 = *(const bf16x8*)(w3l + kc * 4096 + (cohalf * 16 + mrow) * 128 +
                                   (((4 + quad) ^ swz) * 16));
#pragma unroll
      for (int f = 0; f < 4; ++f) {
        if (fbase + f < 7) {
          int pr = (fbase + f) * 16 + mrow;
          bf16x8 a0 = *(const bf16x8*)(Pb + pr * 384 + kc * 128 + ((quad ^ swz) * 16));
          bf16x8 a1 = *(const bf16x8*)(Pb + pr * 384 + kc * 128 + (((4 + quad) ^ swz) * 16));
          acc3[f] = __builtin_amdgcn_mfma_f32_16x16x32_bf16(a0, b0, acc3[f], 0, 0, 0);
          acc3[f] = __builtin_amdgcn_mfma_f32_16x16x32_bf16(a1, b1, acc3[f], 0, 0, 0);
        }
      }
    }
    // BN (no act) + residual, fp32 float4 stores to NCHW
    int h = h0 + rg;
    long obase = ((long)(n * 32 + co3) * 112 + h) * 112;
    const float* xb = x + obase;
    float* ob = out + obase;
#pragma unroll
    for (int f = 0; f < 4; ++f) {
      if (fbase + f < 7) {
        int w0 = (fbase + f) * 16 + quad * 4;
        float4 xv = *(const float4*)(xb + w0);
        float4 o;
        o.x = acc3[f][0] * sc3v + sh3v + xv.x;
        o.y = acc3[f][1] * sc3v + sh3v + xv.y;
        o.z = acc3[f][2] * sc3v + sh3v + xv.z;
        o.w = acc3[f][3] * sc3v + sh3v + xv.w;
        *(float4*)(ob + w0) = o;
      }
    }
    if (rg == 0) {
      asm volatile("s_waitcnt lgkmcnt(0)" ::: "memory");
      __builtin_amdgcn_s_barrier();
      __builtin_amdgcn_sched_barrier(0);
    }
  }
}

// ---------------- launch ---------------------------------------------------
extern "C" void kernel_launch(void* const* d_in, const int* in_sizes, int n_in,
                              void* d_out, int out_size, void* d_ws, size_t ws_size,
                              hipStream_t stream) {
  const float* x  = (const float*)d_in[0];
  const float* w1 = (const float*)d_in[1];
  const float* g1 = (const float*)d_in[2];
  const float* b1 = (const float*)d_in[3];
  const float* m1 = (const float*)d_in[4];
  const float* v1 = (const float*)d_in[5];
  const float* w2 = (const float*)d_in[6];
  const float* g2 = (const float*)d_in[7];
  const float* b2 = (const float*)d_in[8];
  const float* m2 = (const float*)d_in[9];
  const float* v2 = (const float*)d_in[10];
  const float* w3 = (const float*)d_in[11];
  const float* g3 = (const float*)d_in[12];
  const float* b3 = (const float*)d_in[13];
  const float* m3 = (const float*)d_in[14];
  const float* v3 = (const float*)d_in[15];
  float* out = (float*)d_out;

  char* ws = (char*)d_ws;
  double* pa    = (double*)(ws + 256);        // 96 doubles
  double* ps2   = (double*)(ws + 1024);
  double* pc2   = (double*)(ws + 1792);
  float* sc1 = (float*)(ws + 2560);
  float* sh1 = (float*)(ws + 3328);
  float* sc2 = (float*)(ws + 4096);
  float* sh2 = (float*)(ws + 4864);
  float* sc3 = (float*)(ws + 5632);
  float* sh3 = (float*)(ws + 5760);
  __bf16* w1p = (__bf16*)(ws + 8192);         // 12288 B
  __bf16* w3p = (__bf16*)(ws + 20480);        // 12288 B
  __bf16* w2p = (__bf16*)(ws + 32768);        // 663552 B
  __bf16* h1p = (__bf16*)(ws + (1 << 20));    // 79847424 B (padded NHWC)

  hipLaunchKernelGGL(stats_pass1, dim3(96), dim3(256), 0, stream, w1, w2, w3, pa);
  hipLaunchKernelGGL(stats_pass2, dim3(96), dim3(256), 0, stream, w1, w2, w3, pa, ps2, pc2);
  hipLaunchKernelGGL(pack_kernel, dim3(1346), dim3(256), 0, stream, w1, w2, w3,
                     g1, b1, m1, v1, g2, b2, m2, v2, g3, b3, m3, v3, pa, ps2, pc2,
                     w1p, w2p, w3p, sc1, sh1, sc2, sh2, sc3, sh3);
  hipLaunchKernelGGL(conv1_kernel, dim3(112, 16), dim3(256), 0, stream, x, w1p, sc1, sh1, h1p);
  hipLaunchKernelGGL(conv2_kernel, dim3(56, 16), dim3(256), 0, stream, h1p, w2p, sc2, sh2,
                     w3p, sc3, sh3, x, out);
}

// Round 9
// 261.139 us; speedup vs baseline: 1.5404x; 1.0011x over previous
//
#include <hip/hip_runtime.h>

// ---------------------------------------------------------------------------
// TernaryInvertedResidual on MI355X (gfx950) — R13
//
// vs R12 (never ran; desk-check found a cross-wave race: barrier BEFORE the
// per-wave vmcnt gate means wave Y could read smB rows whose staging load
// from wave X was still in flight — R8's verified pattern is gate-THEN-
// barrier). R13 keeps R12's goal (LDS 53760 B -> 3 blocks/CU, 12 waves/CU;
// occupancy was invariant at 17.7% across all schedule changes at 78336 B)
// with a race-free schedule:
//   per tap t: vmcnt(0) [own W(t)/A drained; staged 1 tap earlier, L2-hot]
//     -> s_barrier [block-wide: W(t) visible, tap t-1 reads consumed]
//     -> STAGE_W(t+1) into buf (t+1)&1 [last read at t-1, proven idle]
//     -> aw/av reads -> 42 MFMA (setprio).
//   seam: s_barrier [tap-8 smA reads consumed] -> STAGE_A(cb+1)+STAGE_W(0).
//   One barrier/tap + 1/seam = same count as verified R8.
//   Weights double-buffered (2 x 12288); epilogue w3 b-fragments loaded
//   per-wave from GLOBAL (identical bits; removes the 12 KB w3 LDS buffer).
// Accumulation order identical to R8/R10 -> bit-identical output.
// stats1/stats2/pack/conv1 verbatim from verified R10 (261.4us total).
// ---------------------------------------------------------------------------

typedef __bf16 bf16x8 __attribute__((ext_vector_type(8)));
typedef __bf16 bf16x4 __attribute__((ext_vector_type(4)));
typedef float  f32x4  __attribute__((ext_vector_type(4)));

#define EPSBN 1e-5f

// async global->LDS, 16B per lane; LDS dest = wave-uniform base + lane*16
__device__ __forceinline__ void glds16(const void* g, void* l) {
  __builtin_amdgcn_global_load_lds(
      (const __attribute__((address_space(1))) void*)g,
      (__attribute__((address_space(3))) void*)l, 16, 0, 0);
}

__device__ __forceinline__ __bf16 tern(float w, float delta) {
  float aw = fabsf(w);
  float q = (aw > delta) ? ((w > 0.0f) ? 1.0f : -1.0f) : 0.0f;
  return (__bf16)q;
}

// ---------------- ternarize stats (deterministic, no atomics) --------------
// tensor index: 0=w1 (6144), 1=w2 (331776), 2=w3 (6144)

__global__ void stats_pass1(const float* __restrict__ w1, const float* __restrict__ w2,
                            const float* __restrict__ w3, double* __restrict__ pa) {
  __shared__ double red[256];
  int b = blockIdx.x, tid = threadIdx.x;
  int tix = b >> 5, slice = b & 31;
  const float* w = (tix == 0) ? w1 : (tix == 1) ? w2 : w3;
  int len = (tix == 1) ? 331776 : 6144;
  int per = len >> 5;
  int start = slice * per, end = start + per;
  double s = 0.0;
  for (int i = start + tid; i < end; i += 256) s += (double)fabsf(w[i]);
  red[tid] = s; __syncthreads();
  for (int off = 128; off > 0; off >>= 1) {
    if (tid < off) red[tid] += red[tid + off];
    __syncthreads();
  }
  if (tid == 0) pa[b] = red[0];
}

__global__ void stats_pass2(const float* __restrict__ w1, const float* __restrict__ w2,
                            const float* __restrict__ w3, const double* __restrict__ pa,
                            double* __restrict__ ps2, double* __restrict__ pc2) {
  __shared__ double red[256];
  int b = blockIdx.x, tid = threadIdx.x;
  int tix = b >> 5, slice = b & 31;
  const float* w = (tix == 0) ? w1 : (tix == 1) ? w2 : w3;
  int len = (tix == 1) ? 331776 : 6144;
  double tot = 0.0;
  for (int k = 0; k < 32; ++k) tot += pa[tix * 32 + k];
  float delta = 0.7f * (float)(tot / (double)len);
  int per = len >> 5;
  int start = slice * per, end = start + per;
  double s2 = 0.0, c2 = 0.0;
  for (int i = start + tid; i < end; i += 256) {
    float aw = fabsf(w[i]);
    if (aw > delta) { s2 += (double)aw; c2 += 1.0; }
  }
  red[tid] = s2; __syncthreads();
  for (int off = 128; off > 0; off >>= 1) {
    if (tid < off) red[tid] += red[tid + off];
    __syncthreads();
  }
  if (tid == 0) ps2[b] = red[0];
  __syncthreads();
  red[tid] = c2; __syncthreads();
  for (int off = 128; off > 0; off >>= 1) {
    if (tid < off) red[tid] += red[tid + off];
    __syncthreads();
  }
  if (tid == 0) pc2[b] = red[0];
}

// ---------------- weight pack + BN fold (+ final stats reduce) -------------
// w1p: [co=192][ci=32]  64B rows, 16B-chunk swizzled by ((co>>2)&3)
// w2p: [tap*6+cb][co=192][ci=32]  64B rows, 16B-chunk swizzled by ((co>>2)&3)
// w3p: [kc=3][co=32][ci=64]  128B rows, 16B-chunk swizzled by (co&7)
__global__ void pack_kernel(
    const float* __restrict__ w1, const float* __restrict__ w2, const float* __restrict__ w3,
    const float* __restrict__ g1, const float* __restrict__ b1, const float* __restrict__ m1, const float* __restrict__ v1,
    const float* __restrict__ g2, const float* __restrict__ b2, const float* __restrict__ m2, const float* __restrict__ v2,
    const float* __restrict__ g3, const float* __restrict__ b3, const float* __restrict__ m3, const float* __restrict__ v3,
    const double* __restrict__ pa, const double* __restrict__ ps2, const double* __restrict__ pc2,
    __bf16* __restrict__ w1p, __bf16* __restrict__ w2p, __bf16* __restrict__ w3p,
    float* __restrict__ sc1, float* __restrict__ sh1,
    float* __restrict__ sc2, float* __restrict__ sh2,
    float* __restrict__ sc3, float* __restrict__ sh3) {
  __shared__ float sst[6];
  int tid = threadIdx.x;
  if (tid < 3) {    // per-tensor final reduce (matches old stats_pass3 exactly)
    double tot = 0.0, s2 = 0.0, c2 = 0.0;
    for (int k = 0; k < 32; ++k) {
      tot += pa[tid * 32 + k];
      s2  += ps2[tid * 32 + k];
      c2  += pc2[tid * 32 + k];
    }
    int len = (tid == 1) ? 331776 : 6144;
    sst[tid * 2]     = 0.7f * (float)(tot / (double)len);  // delta
    sst[tid * 2 + 1] = (float)(s2 / fmax(c2, 1.0));        // alpha
  }
  __syncthreads();

  int idx = blockIdx.x * 256 + tid;
  if (idx < 331776) {
    float delta2 = sst[2];
    int c = idx / 6144, rem = idx - c * 6144;
    int co = rem >> 5, r5 = rem & 31;
    int cp = r5 >> 3, lo = r5 & 7;
    int tap = c / 6, cb = c - tap * 6;
    int ci = ((cp ^ ((co >> 2) & 3)) << 3) | lo;   // source-side chunk swizzle
    int cifull = cb * 32 + ci;
    w2p[idx] = tern(w2[(co * 192 + cifull) * 9 + tap], delta2);
    return;
  }
  idx -= 331776;
  if (idx < 6144) {  // w1p, swizzled
    int co = idx >> 5, c = (idx >> 3) & 3, lo = idx & 7;
    int ci = ((c ^ ((co >> 2) & 3)) << 3) | lo;
    w1p[idx] = tern(w1[co * 32 + ci], sst[0]);
    return;
  }
  idx -= 6144;
  if (idx < 6144) {  // w3p, swizzled
    int kc = idx >> 11, rem = idx & 2047;
    int co = rem >> 6, c = (rem >> 3) & 7, lo = rem & 7;
    int ci = ((c ^ (co & 7)) << 3) | lo;
    w3p[idx] = tern(w3[co * 192 + kc * 64 + ci], sst[4]);
    return;
  }
  idx -= 6144;
  if (idx < 192) {
    float rs = rsqrtf(v1[idx] + EPSBN);
    sc1[idx] = g1[idx] * rs * sst[1];
    sh1[idx] = b1[idx] - m1[idx] * g1[idx] * rs;
    return;
  }
  idx -= 192;
  if (idx < 192) {
    float rs = rsqrtf(v2[idx] + EPSBN);
    sc2[idx] = g2[idx] * rs * sst[3];
    sh2[idx] = b2[idx] - m2[idx] * g2[idx] * rs;
    return;
  }
  idx -= 192;
  if (idx < 32) {
    float rs = rsqrtf(v3[idx] + EPSBN);
    sc3[idx] = g3[idx] * rs * sst[5];
    sh3[idx] = b3[idx] - m3[idx] * g3[idx] * rs;
  }
}

// ---------------- conv1 v2: 1x1 (K=32) + fused border zero -----------------
// grid (112 h, 16 n), 256 threads (4 waves). (verbatim from verified R10)
__global__ __launch_bounds__(256)
void conv1_kernel(const float* __restrict__ x, const __bf16* __restrict__ w1p,
                  const float* __restrict__ scale1, const float* __restrict__ shift1,
                  __bf16* __restrict__ h1p) {
  __shared__ __align__(16) char smem[57344];
  char* smA = smem;          // 7168 B acts [w][ci32] 64B rows, chunk-swizzled
  char* smB = smem + 7168;   // 12288 B weights (swizzle baked in w1p)
  char* Pb  = smem;          // 57344 B epilogue union: 112 rows x 512 B
  int tid = threadIdx.x, lane = tid & 63, wave = tid >> 6;
  int h = blockIdx.x, n = blockIdx.y;

  for (int t = wave; t < 12; t += 4)
    glds16((const char*)w1p + t * 1024 + lane * 16, smB + t * 1024);

  // x staging: group g -> ci0=(g/112)*4, w=g%112; 4 coalesced loads, 1 b64 write
  const float* xrow = x + (long)n * 401408 + h * 112;   // + ci*12544 + w
#pragma unroll
  for (int i = 0; i < 4; ++i) {
    int g = i * 256 + tid;
    if (g < 896) {
      int ci0 = (g / 112) * 4, w = g - (g / 112) * 112;
      const float* p = xrow + ci0 * 12544 + w;
      bf16x4 v;
      v[0] = (__bf16)p[0];
      v[1] = (__bf16)p[12544];
      v[2] = (__bf16)p[25088];
      v[3] = (__bf16)p[37632];
      int col = ((ci0 >> 3) ^ ((w >> 2) & 3));
      *(bf16x4*)(smA + w * 64 + (col << 4) + (ci0 & 7) * 2) = v;
    }
  }
  __syncthreads();

  int mrow = lane & 15, quad = lane >> 4;
  int col16 = (quad ^ ((mrow >> 2) & 3)) * 16;
  int c0 = wave * 48;

  bf16x8 aw[3], bv[7];
#pragma unroll
  for (int ic = 0; ic < 3; ++ic)
    aw[ic] = *(const bf16x8*)(smB + (c0 + ic * 16 + mrow) * 64 + col16);
#pragma unroll
  for (int jp = 0; jp < 7; ++jp)
    bv[jp] = *(const bf16x8*)(smA + (jp * 16 + mrow) * 64 + col16);

  // frags now in flight; drain + fence before LDS is reused as P buffer
  asm volatile("s_waitcnt lgkmcnt(0)" ::: "memory");
  __builtin_amdgcn_s_barrier();
  __builtin_amdgcn_sched_barrier(0);

  f32x4 acc[7][3];
#pragma unroll
  for (int jp = 0; jp < 7; ++jp)
#pragma unroll
    for (int ic = 0; ic < 3; ++ic) acc[jp][ic] = (f32x4)0.0f;

#pragma unroll
  for (int jp = 0; jp < 7; ++jp)
#pragma unroll
    for (int ic = 0; ic < 3; ++ic)
      acc[jp][ic] = __builtin_amdgcn_mfma_f32_16x16x32_bf16(aw[ic], bv[jp], acc[jp][ic], 0, 0, 0);

  // epilogue: BN + ReLU6 -> P LDS (padded 512B rows, chunk XOR (w&31))
#pragma unroll
  for (int ic = 0; ic < 3; ++ic) {
    int co0 = c0 + ic * 16 + quad * 4;
    float4 sc = *(const float4*)(scale1 + co0);
    float4 sh = *(const float4*)(shift1 + co0);
    int lch = co0 >> 3;                 // 6*wave + 2*ic + (quad>>1)
    int boff = (quad & 1) * 8;          // (co0&7)*2
#pragma unroll
    for (int jp = 0; jp < 7; ++jp) {
      int w = jp * 16 + mrow;
      bf16x4 o;
      o[0] = (__bf16)fminf(fmaxf(acc[jp][ic][0] * sc.x + sh.x, 0.0f), 6.0f);
      o[1] = (__bf16)fminf(fmaxf(acc[jp][ic][1] * sc.y + sh.y, 0.0f), 6.0f);
      o[2] = (__bf16)fminf(fmaxf(acc[jp][ic][2] * sc.z + sh.z, 0.0f), 6.0f);
      o[3] = (__bf16)fminf(fmaxf(acc[jp][ic][3] * sc.w + sh.w, 0.0f), 6.0f);
      *(bf16x4*)(Pb + w * 512 + ((lch ^ (w & 31)) << 4) + boff) = o;
    }
  }
  asm volatile("s_waitcnt lgkmcnt(0)" ::: "memory");
  __builtin_amdgcn_s_barrier();
  __builtin_amdgcn_sched_barrier(0);

  // coalesced copy-out: interior row = contiguous 2688 x 16B
  __bf16* obase = h1p + ((long)(n * 114 + h + 1) * 114 + 1) * 192;
#pragma unroll
  for (int i = 0; i < 11; ++i) {
    int c = i * 256 + tid;
    if (c < 2688) {
      int w = c / 24, lch = c - w * 24;
      float4 v = *(const float4*)(Pb + w * 512 + ((lch ^ (w & 31)) << 4));
      *(float4*)((char*)obase + c * 16) = v;
    }
  }

  // fused border zeroing of h1p
  float4 z = make_float4(0.f, 0.f, 0.f, 0.f);
  if (tid < 48) {
    int px = (tid < 24) ? 0 : 113;
    int c8 = (tid < 24) ? tid : tid - 24;
    *(float4*)((char*)h1p + ((long)((n * 114 + h + 1) * 114 + px) * 384) + c8 * 16) = z;
  }
  if (h == 0) {
    for (int c = tid; c < 2736; c += 256)
      *(float4*)((char*)h1p + (long)(n * 114) * 114 * 384 + c * 16) = z;
  }
  if (h == 111) {
    for (int c = tid; c < 2736; c += 256)
      *(float4*)((char*)h1p + (long)(n * 114 + 113) * 114 * 384 + c * 16) = z;
  }
}

// ---------------- conv2+conv3 fused, double-buffered (3 blocks/CU) ---------
// grid (56 h-pairs, 16 n), 256 threads (4 waves).
// Per tap t: vmcnt(0) [own W(t)/A done] -> barrier [block-wide visible +
// tap t-1 reads consumed] -> STAGE_W(t+1) into buf (t+1)&1 [last read t-1]
// -> aw/av reads -> 42 MFMA (setprio). Seam: barrier -> STAGE_A+W0.
// Epilogue: P in LDS [0,43008); w3 b-fragments read per-wave from GLOBAL.
// LDS 53760 B -> 3 blocks/CU.

#define STAGE_W(TAP, CB, B) do {                                              \
  _Pragma("unroll")                                                           \
  for (int it_ = 0; it_ < 3; ++it_) {                                         \
    int t_ = wave + it_ * 4;                                                  \
    glds16(w2b + (long)((TAP) * 6 + (CB)) * 12288 + t_ * 1024 + lane * 16,    \
           smBb + (B) * 12288 + t_ * 1024);                                   \
  }                                                                           \
} while (0)

#define STAGE_A(CB) do {                                                      \
  _Pragma("unroll")                                                           \
  for (int it_ = 0; it_ < 8; ++it_)                                           \
    if (aoff[it_] >= 0)                                                       \
      glds16(h1b + aoff[it_] + (CB) * 64, smAb + (wave + it_ * 4) * 1024);    \
} while (0)

__global__ __launch_bounds__(256, 2)
void conv2_kernel(const __bf16* __restrict__ h1p, const __bf16* __restrict__ w2p,
                  const float* __restrict__ scale2, const float* __restrict__ shift2,
                  const __bf16* __restrict__ w3p,
                  const float* __restrict__ scale3, const float* __restrict__ shift3,
                  const float* __restrict__ x, float* __restrict__ out) {
  __shared__ __align__(16) char smem[53760];
  char* smAb = smem;            // 29184 B act window (main loop)
  char* smBb = smem + 29184;    // 2 x 12288 B weights, double-buffered
  char* Pb   = smem;            // 43008 B P-row (epilogue union)
  int tid = threadIdx.x, lane = tid & 63, wave = tid >> 6;
  int bh = blockIdx.x, n = blockIdx.y;
  int h0 = bh * 2;

  // A staging source offsets (bytes, + cb*64 at use); slot s = t*64+lane
  int aoff[8];
#pragma unroll
  for (int it = 0; it < 8; ++it) {
    int t = wave + it * 4;
    int s = t * 64 + lane;
    if (s < 1824) {
      int q = s >> 2, c = s & 3;
      int q_log = c ^ ((q >> 2) & 3);
      int prow = q / 114, pcol = q - prow * 114;
      aoff[it] = ((n * 114 + h0 + prow) * 114 + pcol) * 384 + q_log * 16;
    } else {
      aoff[it] = -1;
    }
  }

  int pg = wave >> 1, cg = wave & 1;
  int mrow = lane & 15, quad = lane >> 4;
  int col16 = (quad ^ ((mrow >> 2) & 3)) * 16;
  const char* h1b = (const char*)h1p;
  const char* w2b = (const char*)w2p;

  f32x4 acc[7][6];
#pragma unroll
  for (int jp = 0; jp < 7; ++jp)
#pragma unroll
    for (int ic = 0; ic < 6; ++ic) acc[jp][ic] = (f32x4)0.0f;

  // prologue: A(0) + W0->buf0 in flight before the first tap
  STAGE_A(0);
  STAGE_W(0, 0, 0);

  for (int cb = 0; cb < 6; ++cb) {
#pragma unroll
    for (int tap = 0; tap < 9; ++tap) {
      // gate own loads BEFORE the barrier (R8 pattern) -> block-wide visible
      asm volatile("s_waitcnt vmcnt(0)" ::: "memory");
      __builtin_amdgcn_s_barrier();
      __builtin_amdgcn_sched_barrier(0);
      if (tap <= 7)
        STAGE_W(tap + 1, cb, (tap + 1) & 1);   // buf last read at tap-1: idle

      const char* bbuf = smBb + (tap & 1) * 12288;
      bf16x8 aw[6];
#pragma unroll
      for (int ic = 0; ic < 6; ++ic)
        aw[ic] = *(const bf16x8*)(bbuf + (cg * 96 + ic * 16 + mrow) * 64 + col16);

      int dy = tap / 3, dx = tap - dy * 3;
      int base = (pg + dy) * 114 + dx;
      __builtin_amdgcn_s_setprio(1);
#pragma unroll
      for (int jp = 0; jp < 7; ++jp) {
        int row = base + jp * 16 + mrow;
        bf16x8 av = *(const bf16x8*)(smAb + row * 64 +
                                     ((quad ^ ((row >> 2) & 3)) * 16));
#pragma unroll
        for (int ic = 0; ic < 6; ++ic)
          acc[jp][ic] = __builtin_amdgcn_mfma_f32_16x16x32_bf16(aw[ic], av, acc[jp][ic], 0, 0, 0);
      }
      __builtin_amdgcn_s_setprio(0);
    }

    // seam: all waves issued tap-8 MFMAs at this barrier -> smA reads done
    if (cb < 5) {
      __builtin_amdgcn_s_barrier();
      __builtin_amdgcn_sched_barrier(0);
      STAGE_A(cb + 1);
      STAGE_W(0, cb + 1, 0);
    }
  }

  // ---------------- fused conv3 epilogue ----------------------------------
  // (P union overlaps main-loop LDS; drain + barrier orders all reads first)
  asm volatile("s_waitcnt lgkmcnt(0)" ::: "memory");
  __builtin_amdgcn_s_barrier();
  __builtin_amdgcn_sched_barrier(0);

  // per-lane conv3 BN params: co = (wave&1)*16 + mrow
  int cohalf = wave & 1;
  int co3 = cohalf * 16 + mrow;
  float sc3v = scale3[co3], sh3v = shift3[co3];
  int fbase = (wave >> 1) * 4;             // waves 0,1 -> frags 0..3; 2,3 -> 4..6
  int swz = mrow & 7;

  // w3 b-fragments straight from global (same bits as the old LDS stage)
  bf16x8 wb0[3], wb1[3];
#pragma unroll
  for (int kc = 0; kc < 3; ++kc) {
    wb0[kc] = *(const bf16x8*)((const char*)w3p + kc * 4096 +
                               (cohalf * 16 + mrow) * 128 + ((quad ^ swz) * 16));
    wb1[kc] = *(const bf16x8*)((const char*)w3p + kc * 4096 +
                               (cohalf * 16 + mrow) * 128 + (((4 + quad) ^ swz) * 16));
  }

#pragma unroll
  for (int rg = 0; rg < 2; ++rg) {
    if (pg == rg) {
      // write this wave's half (cg) of P-row rg
#pragma unroll
      for (int ic = 0; ic < 6; ++ic) {
        int co0 = cg * 96 + ic * 16 + quad * 4;
        float4 sc = *(const float4*)(scale2 + co0);
        float4 sh = *(const float4*)(shift2 + co0);
        int kc = co0 >> 6, c6 = co0 & 63;
        int chunk = c6 >> 3, off = c6 & 7;
#pragma unroll
        for (int jp = 0; jp < 7; ++jp) {
          int px = jp * 16 + mrow;
          bf16x4 o;
          o[0] = (__bf16)fminf(fmaxf(acc[jp][ic][0] * sc.x + sh.x, 0.0f), 6.0f);
          o[1] = (__bf16)fminf(fmaxf(acc[jp][ic][1] * sc.y + sh.y, 0.0f), 6.0f);
          o[2] = (__bf16)fminf(fmaxf(acc[jp][ic][2] * sc.z + sh.z, 0.0f), 6.0f);
          o[3] = (__bf16)fminf(fmaxf(acc[jp][ic][3] * sc.w + sh.w, 0.0f), 6.0f);
          *(bf16x4*)(Pb + px * 384 + kc * 128 + ((chunk ^ (px & 7)) * 16) + off * 2) = o;
        }
      }
    }
    asm volatile("s_waitcnt lgkmcnt(0)" ::: "memory");
    __builtin_amdgcn_s_barrier();
    __builtin_amdgcn_sched_barrier(0);

    // conv3 on row rg: wave covers co 16*(wave&1).. and px frags fbase..(+3|+2)
    f32x4 acc3[4];
#pragma unroll
    for (int f = 0; f < 4; ++f) acc3[f] = (f32x4)0.0f;
#pragma unroll
    for (int kc = 0; kc < 3; ++kc) {
#pragma unroll
      for (int f = 0; f < 4; ++f) {
        if (fbase + f < 7) {
          int pr = (fbase + f) * 16 + mrow;
          bf16x8 a0 = *(const bf16x8*)(Pb + pr * 384 + kc * 128 + ((quad ^ swz) * 16));
          bf16x8 a1 = *(const bf16x8*)(Pb + pr * 384 + kc * 128 + (((4 + quad) ^ swz) * 16));
          acc3[f] = __builtin_amdgcn_mfma_f32_16x16x32_bf16(a0, wb0[kc], acc3[f], 0, 0, 0);
          acc3[f] = __builtin_amdgcn_mfma_f32_16x16x32_bf16(a1, wb1[kc], acc3[f], 0, 0, 0);
        }
      }
    }
    // BN (no act) + residual, fp32 float4 stores to NCHW
    int h = h0 + rg;
    long obase = ((long)(n * 32 + co3) * 112 + h) * 112;
    const float* xb = x + obase;
    float* ob = out + obase;
#pragma unroll
    for (int f = 0; f < 4; ++f) {
      if (fbase + f < 7) {
        int w0 = (fbase + f) * 16 + quad * 4;
        float4 xv = *(const float4*)(xb + w0);
        float4 o;
        o.x = acc3[f][0] * sc3v + sh3v + xv.x;
        o.y = acc3[f][1] * sc3v + sh3v + xv.y;
        o.z = acc3[f][2] * sc3v + sh3v + xv.z;
        o.w = acc3[f][3] * sc3v + sh3v + xv.w;
        *(float4*)(ob + w0) = o;
      }
    }
    if (rg == 0) {
      asm volatile("s_waitcnt lgkmcnt(0)" ::: "memory");
      __builtin_amdgcn_s_barrier();
      __builtin_amdgcn_sched_barrier(0);
    }
  }
}

// ---------------- launch ---------------------------------------------------
extern "C" void kernel_launch(void* const* d_in, const int* in_sizes, int n_in,
                              void* d_out, int out_size, void* d_ws, size_t ws_size,
                              hipStream_t stream) {
  const float* x  = (const float*)d_in[0];
  const float* w1 = (const float*)d_in[1];
  const float* g1 = (const float*)d_in[2];
  const float* b1 = (const float*)d_in[3];
  const float* m1 = (const float*)d_in[4];
  const float* v1 = (const float*)d_in[5];
  const float* w2 = (const float*)d_in[6];
  const float* g2 = (const float*)d_in[7];
  const float* b2 = (const float*)d_in[8];
  const float* m2 = (const float*)d_in[9];
  const float* v2 = (const float*)d_in[10];
  const float* w3 = (const float*)d_in[11];
  const float* g3 = (const float*)d_in[12];
  const float* b3 = (const float*)d_in[13];
  const float* m3 = (const float*)d_in[14];
  const float* v3 = (const float*)d_in[15];
  float* out = (float*)d_out;

  char* ws = (char*)d_ws;
  double* pa    = (double*)(ws + 256);        // 96 doubles
  double* ps2   = (double*)(ws + 1024);
  double* pc2   = (double*)(ws + 1792);
  float* sc1 = (float*)(ws + 2560);
  float* sh1 = (float*)(ws + 3328);
  float* sc2 = (float*)(ws + 4096);
  float* sh2 = (float*)(ws + 4864);
  float* sc3 = (float*)(ws + 5632);
  float* sh3 = (float*)(ws + 5760);
  __bf16* w1p = (__bf16*)(ws + 8192);         // 12288 B
  __bf16* w3p = (__bf16*)(ws + 20480);        // 12288 B
  __bf16* w2p = (__bf16*)(ws + 32768);        // 663552 B
  __bf16* h1p = (__bf16*)(ws + (1 << 20));    // 79847424 B (padded NHWC)

  hipLaunchKernelGGL(stats_pass1, dim3(96), dim3(256), 0, stream, w1, w2, w3, pa);
  hipLaunchKernelGGL(stats_pass2, dim3(96), dim3(256), 0, stream, w1, w2, w3, pa, ps2, pc2);
  hipLaunchKernelGGL(pack_kernel, dim3(1346), dim3(256), 0, stream, w1, w2, w3,
                     g1, b1, m1, v1, g2, b2, m2, v2, g3, b3, m3, v3, pa, ps2, pc2,
                     w1p, w2p, w3p, sc1, sh1, sc2, sh2, sc3, sh3);
  hipLaunchKernelGGL(conv1_kernel, dim3(112, 16), dim3(256), 0, stream, x, w1p, sc1, sh1, h1p);
  hipLaunchKernelGGL(conv2_kernel, dim3(56, 16), dim3(256), 0, stream, h1p, w2p, sc2, sh2,
                     w3p, sc3, sh3, x, out);
}

// Round 10
// 258.810 us; speedup vs baseline: 1.5543x; 1.0090x over previous
//
#include <hip/hip_runtime.h>

// ---------------------------------------------------------------------------
// TernaryInvertedResidual on MI355X (gfx950) — R14
//
// vs R13 (verified 261.1us; conv2=132.7us): launch consolidation, all math
// bit-identical:
//   * stats2 MERGED into pack (one kernel, 1440 blocks): blocks 0-95 run
//     stats2 verbatim; blocks 96+ pack weights. Weight ternarization needs
//     only DELTA (alpha folds into BN scale), and delta is recomputed
//     per-block from pa with the identical k-ascending reduce.
//   * BN-const production moved into conv1: every block computes alpha1 +
//     sc1/sh1 into LDS (identical expressions); block (0,0) also writes
//     sc2/sh2/sc3/sh3 to ws (stream order covers conv2).
//   5 launches -> 4.
// conv2_kernel byte-identical to R13 (double-buffered W, 53760 B LDS,
// 3 blocks/CU, gate-then-barrier, conv3-fused epilogue).
// ---------------------------------------------------------------------------

typedef __bf16 bf16x8 __attribute__((ext_vector_type(8)));
typedef __bf16 bf16x4 __attribute__((ext_vector_type(4)));
typedef float  f32x4  __attribute__((ext_vector_type(4)));

#define EPSBN 1e-5f

// async global->LDS, 16B per lane; LDS dest = wave-uniform base + lane*16
__device__ __forceinline__ void glds16(const void* g, void* l) {
  __builtin_amdgcn_global_load_lds(
      (const __attribute__((address_space(1))) void*)g,
      (__attribute__((address_space(3))) void*)l, 16, 0, 0);
}

__device__ __forceinline__ __bf16 tern(float w, float delta) {
  float aw = fabsf(w);
  float q = (aw > delta) ? ((w > 0.0f) ? 1.0f : -1.0f) : 0.0f;
  return (__bf16)q;
}

// ---------------- stats pass 1 (abs-sum partials) --------------------------
// tensor index: 0=w1 (6144), 1=w2 (331776), 2=w3 (6144)
__global__ void stats_pass1(const float* __restrict__ w1, const float* __restrict__ w2,
                            const float* __restrict__ w3, double* __restrict__ pa) {
  __shared__ double red[256];
  int b = blockIdx.x, tid = threadIdx.x;
  int tix = b >> 5, slice = b & 31;
  const float* w = (tix == 0) ? w1 : (tix == 1) ? w2 : w3;
  int len = (tix == 1) ? 331776 : 6144;
  int per = len >> 5;
  int start = slice * per, end = start + per;
  double s = 0.0;
  for (int i = start + tid; i < end; i += 256) s += (double)fabsf(w[i]);
  red[tid] = s; __syncthreads();
  for (int off = 128; off > 0; off >>= 1) {
    if (tid < off) red[tid] += red[tid + off];
    __syncthreads();
  }
  if (tid == 0) pa[b] = red[0];
}

// ---------------- stats pass 2 + weight pack (merged) ----------------------
// blocks 0..95: stats2 partials (verbatim). blocks 96..1439: weight packing
// (needs only delta, recomputed per-block from pa with identical reduce).
// w1p: [co=192][ci=32]  64B rows, swizzled by ((co>>2)&3)
// w2p: [tap*6+cb][co=192][ci=32]  64B rows, swizzled by ((co>>2)&3)
// w3p: [kc=3][co=32][ci=64]  128B rows, swizzled by (co&7)
__global__ void stats2_pack_kernel(
    const float* __restrict__ w1, const float* __restrict__ w2, const float* __restrict__ w3,
    const double* __restrict__ pa, double* __restrict__ ps2, double* __restrict__ pc2,
    __bf16* __restrict__ w1p, __bf16* __restrict__ w2p, __bf16* __restrict__ w3p) {
  __shared__ double red[256];
  __shared__ float sdelta[3];
  int b = blockIdx.x, tid = threadIdx.x;

  if (b < 96) {   // ---- stats2, verbatim from the verified kernel ----
    int tix = b >> 5, slice = b & 31;
    const float* w = (tix == 0) ? w1 : (tix == 1) ? w2 : w3;
    int len = (tix == 1) ? 331776 : 6144;
    double tot = 0.0;
    for (int k = 0; k < 32; ++k) tot += pa[tix * 32 + k];
    float delta = 0.7f * (float)(tot / (double)len);
    int per = len >> 5;
    int start = slice * per, end = start + per;
    double s2 = 0.0, c2 = 0.0;
    for (int i = start + tid; i < end; i += 256) {
      float aw = fabsf(w[i]);
      if (aw > delta) { s2 += (double)aw; c2 += 1.0; }
    }
    red[tid] = s2; __syncthreads();
    for (int off = 128; off > 0; off >>= 1) {
      if (tid < off) red[tid] += red[tid + off];
      __syncthreads();
    }
    if (tid == 0) ps2[b] = red[0];
    __syncthreads();
    red[tid] = c2; __syncthreads();
    for (int off = 128; off > 0; off >>= 1) {
      if (tid < off) red[tid] += red[tid + off];
      __syncthreads();
    }
    if (tid == 0) pc2[b] = red[0];
    return;
  }

  // ---- weight packing (delta-only; identical expressions) ----
  if (tid < 3) {
    double tot = 0.0;
    for (int k = 0; k < 32; ++k) tot += pa[tid * 32 + k];
    int len = (tid == 1) ? 331776 : 6144;
    sdelta[tid] = 0.7f * (float)(tot / (double)len);
  }
  __syncthreads();

  int idx = (b - 96) * 256 + tid;          // 0 .. 344063
  if (idx < 331776) {
    float delta2 = sdelta[1];
    int c = idx / 6144, rem = idx - c * 6144;
    int co = rem >> 5, r5 = rem & 31;
    int cp = r5 >> 3, lo = r5 & 7;
    int tap = c / 6, cb = c - tap * 6;
    int ci = ((cp ^ ((co >> 2) & 3)) << 3) | lo;   // source-side chunk swizzle
    int cifull = cb * 32 + ci;
    w2p[idx] = tern(w2[(co * 192 + cifull) * 9 + tap], delta2);
    return;
  }
  idx -= 331776;
  if (idx < 6144) {  // w1p, swizzled
    int co = idx >> 5, c = (idx >> 3) & 3, lo = idx & 7;
    int ci = ((c ^ ((co >> 2) & 3)) << 3) | lo;
    w1p[idx] = tern(w1[co * 32 + ci], sdelta[0]);
    return;
  }
  idx -= 6144;
  if (idx < 6144) {  // w3p, swizzled
    int kc = idx >> 11, rem = idx & 2047;
    int co = rem >> 6, c = (rem >> 3) & 7, lo = rem & 7;
    int ci = ((c ^ (co & 7)) << 3) | lo;
    w3p[idx] = tern(w3[co * 192 + kc * 64 + ci], sdelta[2]);
  }
}

// ---------------- conv1 + BN-const production ------------------------------
// grid (112 h, 16 n), 256 threads (4 waves). Body verbatim from verified
// R10/R13 conv1 v2, except: sc1/sh1 computed in-block into LDS (identical
// expressions), and block (0,0) writes sc2/sh2/sc3/sh3 to ws for conv2.
__global__ __launch_bounds__(256)
void conv1_kernel(const float* __restrict__ x, const __bf16* __restrict__ w1p,
                  const float* __restrict__ g1, const float* __restrict__ b1,
                  const float* __restrict__ m1, const float* __restrict__ v1,
                  const double* __restrict__ ps2, const double* __restrict__ pc2,
                  const float* __restrict__ g2, const float* __restrict__ b2,
                  const float* __restrict__ m2, const float* __restrict__ v2,
                  const float* __restrict__ g3, const float* __restrict__ b3,
                  const float* __restrict__ m3, const float* __restrict__ v3,
                  float* __restrict__ sc2, float* __restrict__ sh2,
                  float* __restrict__ sc3, float* __restrict__ sh3,
                  __bf16* __restrict__ h1p) {
  __shared__ __align__(16) char smem[57344];
  __shared__ float salpha[3];
  __shared__ __align__(16) float sc1l[192];
  __shared__ __align__(16) float sh1l[192];
  char* smA = smem;          // 7168 B acts [w][ci32] 64B rows, chunk-swizzled
  char* smB = smem + 7168;   // 12288 B weights (swizzle baked in w1p)
  char* Pb  = smem;          // 57344 B epilogue union: 112 rows x 512 B
  int tid = threadIdx.x, lane = tid & 63, wave = tid >> 6;
  int h = blockIdx.x, n = blockIdx.y;

  for (int t = wave; t < 12; t += 4)
    glds16((const char*)w1p + t * 1024 + lane * 16, smB + t * 1024);

  // alphas (identical k-order to old stats_pass3) + BN1 consts into LDS
  if (tid < 3) {
    double s2 = 0.0, c2 = 0.0;
    for (int k = 0; k < 32; ++k) {
      s2 += ps2[tid * 32 + k];
      c2 += pc2[tid * 32 + k];
    }
    salpha[tid] = (float)(s2 / fmax(c2, 1.0));
  }
  __syncthreads();
  if (tid < 192) {
    float rs = rsqrtf(v1[tid] + EPSBN);
    sc1l[tid] = g1[tid] * rs * salpha[0];
    sh1l[tid] = b1[tid] - m1[tid] * g1[tid] * rs;
  }
  // block (0,0): produce conv2/conv3 BN consts (stream order covers conv2)
  if (h == 0 && n == 0) {
    if (tid < 192) {
      float rs = rsqrtf(v2[tid] + EPSBN);
      sc2[tid] = g2[tid] * rs * salpha[1];
      sh2[tid] = b2[tid] - m2[tid] * g2[tid] * rs;
    } else if (tid < 224) {
      int j = tid - 192;
      float rs = rsqrtf(v3[j] + EPSBN);
      sc3[j] = g3[j] * rs * salpha[2];
      sh3[j] = b3[j] - m3[j] * g3[j] * rs;
    }
  }

  // x staging: group g -> ci0=(g/112)*4, w=g%112; 4 coalesced loads, 1 b64 write
  const float* xrow = x + (long)n * 401408 + h * 112;   // + ci*12544 + w
#pragma unroll
  for (int i = 0; i < 4; ++i) {
    int g = i * 256 + tid;
    if (g < 896) {
      int ci0 = (g / 112) * 4, w = g - (g / 112) * 112;
      const float* p = xrow + ci0 * 12544 + w;
      bf16x4 v;
      v[0] = (__bf16)p[0];
      v[1] = (__bf16)p[12544];
      v[2] = (__bf16)p[25088];
      v[3] = (__bf16)p[37632];
      int col = ((ci0 >> 3) ^ ((w >> 2) & 3));
      *(bf16x4*)(smA + w * 64 + (col << 4) + (ci0 & 7) * 2) = v;
    }
  }
  __syncthreads();

  int mrow = lane & 15, quad = lane >> 4;
  int col16 = (quad ^ ((mrow >> 2) & 3)) * 16;
  int c0 = wave * 48;

  bf16x8 aw[3], bv[7];
#pragma unroll
  for (int ic = 0; ic < 3; ++ic)
    aw[ic] = *(const bf16x8*)(smB + (c0 + ic * 16 + mrow) * 64 + col16);
#pragma unroll
  for (int jp = 0; jp < 7; ++jp)
    bv[jp] = *(const bf16x8*)(smA + (jp * 16 + mrow) * 64 + col16);

  // frags now in flight; drain + fence before LDS is reused as P buffer
  asm volatile("s_waitcnt lgkmcnt(0)" ::: "memory");
  __builtin_amdgcn_s_barrier();
  __builtin_amdgcn_sched_barrier(0);

  f32x4 acc[7][3];
#pragma unroll
  for (int jp = 0; jp < 7; ++jp)
#pragma unroll
    for (int ic = 0; ic < 3; ++ic) acc[jp][ic] = (f32x4)0.0f;

#pragma unroll
  for (int jp = 0; jp < 7; ++jp)
#pragma unroll
    for (int ic = 0; ic < 3; ++ic)
      acc[jp][ic] = __builtin_amdgcn_mfma_f32_16x16x32_bf16(aw[ic], bv[jp], acc[jp][ic], 0, 0, 0);

  // epilogue: BN + ReLU6 -> P LDS (padded 512B rows, chunk XOR (w&31))
#pragma unroll
  for (int ic = 0; ic < 3; ++ic) {
    int co0 = c0 + ic * 16 + quad * 4;
    float4 sc = *(const float4*)(sc1l + co0);
    float4 sh = *(const float4*)(sh1l + co0);
    int lch = co0 >> 3;                 // 6*wave + 2*ic + (quad>>1)
    int boff = (quad & 1) * 8;          // (co0&7)*2
#pragma unroll
    for (int jp = 0; jp < 7; ++jp) {
      int w = jp * 16 + mrow;
      bf16x4 o;
      o[0] = (__bf16)fminf(fmaxf(acc[jp][ic][0] * sc.x + sh.x, 0.0f), 6.0f);
      o[1] = (__bf16)fminf(fmaxf(acc[jp][ic][1] * sc.y + sh.y, 0.0f), 6.0f);
      o[2] = (__bf16)fminf(fmaxf(acc[jp][ic][2] * sc.z + sh.z, 0.0f), 6.0f);
      o[3] = (__bf16)fminf(fmaxf(acc[jp][ic][3] * sc.w + sh.w, 0.0f), 6.0f);
      *(bf16x4*)(Pb + w * 512 + ((lch ^ (w & 31)) << 4) + boff) = o;
    }
  }
  asm volatile("s_waitcnt lgkmcnt(0)" ::: "memory");
  __builtin_amdgcn_s_barrier();
  __builtin_amdgcn_sched_barrier(0);

  // coalesced copy-out: interior row = contiguous 2688 x 16B
  __bf16* obase = h1p + ((long)(n * 114 + h + 1) * 114 + 1) * 192;
#pragma unroll
  for (int i = 0; i < 11; ++i) {
    int c = i * 256 + tid;
    if (c < 2688) {
      int w = c / 24, lch = c - w * 24;
      float4 v = *(const float4*)(Pb + w * 512 + ((lch ^ (w & 31)) << 4));
      *(float4*)((char*)obase + c * 16) = v;
    }
  }

  // fused border zeroing of h1p
  float4 z = make_float4(0.f, 0.f, 0.f, 0.f);
  if (tid < 48) {
    int px = (tid < 24) ? 0 : 113;
    int c8 = (tid < 24) ? tid : tid - 24;
    *(float4*)((char*)h1p + ((long)((n * 114 + h + 1) * 114 + px) * 384) + c8 * 16) = z;
  }
  if (h == 0) {
    for (int c = tid; c < 2736; c += 256)
      *(float4*)((char*)h1p + (long)(n * 114) * 114 * 384 + c * 16) = z;
  }
  if (h == 111) {
    for (int c = tid; c < 2736; c += 256)
      *(float4*)((char*)h1p + (long)(n * 114 + 113) * 114 * 384 + c * 16) = z;
  }
}

// ---------------- conv2+conv3 fused (byte-identical to verified R13) -------
// grid (56 h-pairs, 16 n), 256 threads (4 waves).
// Per tap t: vmcnt(0) [own W(t)/A done] -> barrier [block-wide visible +
// tap t-1 reads consumed] -> STAGE_W(t+1) into buf (t+1)&1 [last read t-1]
// -> aw/av reads -> 42 MFMA (setprio). Seam: barrier -> STAGE_A+W0.
// Epilogue: P in LDS [0,43008); w3 b-fragments read per-wave from GLOBAL.
// LDS 53760 B -> 3 blocks/CU.

#define STAGE_W(TAP, CB, B) do {                                              \
  _Pragma("unroll")                                                           \
  for (int it_ = 0; it_ < 3; ++it_) {                                         \
    int t_ = wave + it_ * 4;                                                  \
    glds16(w2b + (long)((TAP) * 6 + (CB)) * 12288 + t_ * 1024 + lane * 16,    \
           smBb + (B) * 12288 + t_ * 1024);                                   \
  }                                                                           \
} while (0)

#define STAGE_A(CB) do {                                                      \
  _Pragma("unroll")                                                           \
  for (int it_ = 0; it_ < 8; ++it_)                                           \
    if (aoff[it_] >= 0)                                                       \
      glds16(h1b + aoff[it_] + (CB) * 64, smAb + (wave + it_ * 4) * 1024);    \
} while (0)

__global__ __launch_bounds__(256, 2)
void conv2_kernel(const __bf16* __restrict__ h1p, const __bf16* __restrict__ w2p,
                  const float* __restrict__ scale2, const float* __restrict__ shift2,
                  const __bf16* __restrict__ w3p,
                  const float* __restrict__ scale3, const float* __restrict__ shift3,
                  const float* __restrict__ x, float* __restrict__ out) {
  __shared__ __align__(16) char smem[53760];
  char* smAb = smem;            // 29184 B act window (main loop)
  char* smBb = smem + 29184;    // 2 x 12288 B weights, double-buffered
  char* Pb   = smem;            // 43008 B P-row (epilogue union)
  int tid = threadIdx.x, lane = tid & 63, wave = tid >> 6;
  int bh = blockIdx.x, n = blockIdx.y;
  int h0 = bh * 2;

  // A staging source offsets (bytes, + cb*64 at use); slot s = t*64+lane
  int aoff[8];
#pragma unroll
  for (int it = 0; it < 8; ++it) {
    int t = wave + it * 4;
    int s = t * 64 + lane;
    if (s < 1824) {
      int q = s >> 2, c = s & 3;
      int q_log = c ^ ((q >> 2) & 3);
      int prow = q / 114, pcol = q - prow * 114;
      aoff[it] = ((n * 114 + h0 + prow) * 114 + pcol) * 384 + q_log * 16;
    } else {
      aoff[it] = -1;
    }
  }

  int pg = wave >> 1, cg = wave & 1;
  int mrow = lane & 15, quad = lane >> 4;
  int col16 = (quad ^ ((mrow >> 2) & 3)) * 16;
  const char* h1b = (const char*)h1p;
  const char* w2b = (const char*)w2p;

  f32x4 acc[7][6];
#pragma unroll
  for (int jp = 0; jp < 7; ++jp)
#pragma unroll
    for (int ic = 0; ic < 6; ++ic) acc[jp][ic] = (f32x4)0.0f;

  // prologue: A(0) + W0->buf0 in flight before the first tap
  STAGE_A(0);
  STAGE_W(0, 0, 0);

  for (int cb = 0; cb < 6; ++cb) {
#pragma unroll
    for (int tap = 0; tap < 9; ++tap) {
      // gate own loads BEFORE the barrier (R8 pattern) -> block-wide visible
      asm volatile("s_waitcnt vmcnt(0)" ::: "memory");
      __builtin_amdgcn_s_barrier();
      __builtin_amdgcn_sched_barrier(0);
      if (tap <= 7)
        STAGE_W(tap + 1, cb, (tap + 1) & 1);   // buf last read at tap-1: idle

      const char* bbuf = smBb + (tap & 1) * 12288;
      bf16x8 aw[6];
#pragma unroll
      for (int ic = 0; ic < 6; ++ic)
        aw[ic] = *(const bf16x8*)(bbuf + (cg * 96 + ic * 16 + mrow) * 64 + col16);

      int dy = tap / 3, dx = tap - dy * 3;
      int base = (pg + dy) * 114 + dx;
      __builtin_amdgcn_s_setprio(1);
#pragma unroll
      for (int jp = 0; jp < 7; ++jp) {
        int row = base + jp * 16 + mrow;
        bf16x8 av = *(const bf16x8*)(smAb + row * 64 +
                                     ((quad ^ ((row >> 2) & 3)) * 16));
#pragma unroll
        for (int ic = 0; ic < 6; ++ic)
          acc[jp][ic] = __builtin_amdgcn_mfma_f32_16x16x32_bf16(aw[ic], av, acc[jp][ic], 0, 0, 0);
      }
      __builtin_amdgcn_s_setprio(0);
    }

    // seam: all waves issued tap-8 MFMAs at this barrier -> smA reads done
    if (cb < 5) {
      __builtin_amdgcn_s_barrier();
      __builtin_amdgcn_sched_barrier(0);
      STAGE_A(cb + 1);
      STAGE_W(0, cb + 1, 0);
    }
  }

  // ---------------- fused conv3 epilogue ----------------------------------
  // (P union overlaps main-loop LDS; drain + barrier orders all reads first)
  asm volatile("s_waitcnt lgkmcnt(0)" ::: "memory");
  __builtin_amdgcn_s_barrier();
  __builtin_amdgcn_sched_barrier(0);

  // per-lane conv3 BN params: co = (wave&1)*16 + mrow
  int cohalf = wave & 1;
  int co3 = cohalf * 16 + mrow;
  float sc3v = scale3[co3], sh3v = shift3[co3];
  int fbase = (wave >> 1) * 4;             // waves 0,1 -> frags 0..3; 2,3 -> 4..6
  int swz = mrow & 7;

  // w3 b-fragments straight from global (same bits as the old LDS stage)
  bf16x8 wb0[3], wb1[3];
#pragma unroll
  for (int kc = 0; kc < 3; ++kc) {
    wb0[kc] = *(const bf16x8*)((const char*)w3p + kc * 4096 +
                               (cohalf * 16 + mrow) * 128 + ((quad ^ swz) * 16));
    wb1[kc] = *(const bf16x8*)((const char*)w3p + kc * 4096 +
                               (cohalf * 16 + mrow) * 128 + (((4 + quad) ^ swz) * 16));
  }

#pragma unroll
  for (int rg = 0; rg < 2; ++rg) {
    if (pg == rg) {
      // write this wave's half (cg) of P-row rg
#pragma unroll
      for (int ic = 0; ic < 6; ++ic) {
        int co0 = cg * 96 + ic * 16 + quad * 4;
        float4 sc = *(const float4*)(scale2 + co0);
        float4 sh = *(const float4*)(shift2 + co0);
        int kc = co0 >> 6, c6 = co0 & 63;
        int chunk = c6 >> 3, off = c6 & 7;
#pragma unroll
        for (int jp = 0; jp < 7; ++jp) {
          int px = jp * 16 + mrow;
          bf16x4 o;
          o[0] = (__bf16)fminf(fmaxf(acc[jp][ic][0] * sc.x + sh.x, 0.0f), 6.0f);
          o[1] = (__bf16)fminf(fmaxf(acc[jp][ic][1] * sc.y + sh.y, 0.0f), 6.0f);
          o[2] = (__bf16)fminf(fmaxf(acc[jp][ic][2] * sc.z + sh.z, 0.0f), 6.0f);
          o[3] = (__bf16)fminf(fmaxf(acc[jp][ic][3] * sc.w + sh.w, 0.0f), 6.0f);
          *(bf16x4*)(Pb + px * 384 + kc * 128 + ((chunk ^ (px & 7)) * 16) + off * 2) = o;
        }
      }
    }
    asm volatile("s_waitcnt lgkmcnt(0)" ::: "memory");
    __builtin_amdgcn_s_barrier();
    __builtin_amdgcn_sched_barrier(0);

    // conv3 on row rg: wave covers co 16*(wave&1).. and px frags fbase..(+3|+2)
    f32x4 acc3[4];
#pragma unroll
    for (int f = 0; f < 4; ++f) acc3[f] = (f32x4)0.0f;
#pragma unroll
    for (int kc = 0; kc < 3; ++kc) {
#pragma unroll
      for (int f = 0; f < 4; ++f) {
        if (fbase + f < 7) {
          int pr = (fbase + f) * 16 + mrow;
          bf16x8 a0 = *(const bf16x8*)(Pb + pr * 384 + kc * 128 + ((quad ^ swz) * 16));
          bf16x8 a1 = *(const bf16x8*)(Pb + pr * 384 + kc * 128 + (((4 + quad) ^ swz) * 16));
          acc3[f] = __builtin_amdgcn_mfma_f32_16x16x32_bf16(a0, wb0[kc], acc3[f], 0, 0, 0);
          acc3[f] = __builtin_amdgcn_mfma_f32_16x16x32_bf16(a1, wb1[kc], acc3[f], 0, 0, 0);
        }
      }
    }
    // BN (no act) + residual, fp32 float4 stores to NCHW
    int h = h0 + rg;
    long obase = ((long)(n * 32 + co3) * 112 + h) * 112;
    const float* xb = x + obase;
    float* ob = out + obase;
#pragma unroll
    for (int f = 0; f < 4; ++f) {
      if (fbase + f < 7) {
        int w0 = (fbase + f) * 16 + quad * 4;
        float4 xv = *(const float4*)(xb + w0);
        float4 o;
        o.x = acc3[f][0] * sc3v + sh3v + xv.x;
        o.y = acc3[f][1] * sc3v + sh3v + xv.y;
        o.z = acc3[f][2] * sc3v + sh3v + xv.z;
        o.w = acc3[f][3] * sc3v + sh3v + xv.w;
        *(float4*)(ob + w0) = o;
      }
    }
    if (rg == 0) {
      asm volatile("s_waitcnt lgkmcnt(0)" ::: "memory");
      __builtin_amdgcn_s_barrier();
      __builtin_amdgcn_sched_barrier(0);
    }
  }
}

// ---------------- launch ---------------------------------------------------
extern "C" void kernel_launch(void* const* d_in, const int* in_sizes, int n_in,
                              void* d_out, int out_size, void* d_ws, size_t ws_size,
                              hipStream_t stream) {
  const float* x  = (const float*)d_in[0];
  const float* w1 = (const float*)d_in[1];
  const float* g1 = (const float*)d_in[2];
  const float* b1 = (const float*)d_in[3];
  const float* m1 = (const float*)d_in[4];
  const float* v1 = (const float*)d_in[5];
  const float* w2 = (const float*)d_in[6];
  const float* g2 = (const float*)d_in[7];
  const float* b2 = (const float*)d_in[8];
  const float* m2 = (const float*)d_in[9];
  const float* v2 = (const float*)d_in[10];
  const float* w3 = (const float*)d_in[11];
  const float* g3 = (const float*)d_in[12];
  const float* b3 = (const float*)d_in[13];
  const float* m3 = (const float*)d_in[14];
  const float* v3 = (const float*)d_in[15];
  float* out = (float*)d_out;

  char* ws = (char*)d_ws;
  double* pa    = (double*)(ws + 256);        // 96 doubles
  double* ps2   = (double*)(ws + 1024);
  double* pc2   = (double*)(ws + 1792);
  float* sc2 = (float*)(ws + 4096);
  float* sh2 = (float*)(ws + 4864);
  float* sc3 = (float*)(ws + 5632);
  float* sh3 = (float*)(ws + 5760);
  __bf16* w1p = (__bf16*)(ws + 8192);         // 12288 B
  __bf16* w3p = (__bf16*)(ws + 20480);        // 12288 B
  __bf16* w2p = (__bf16*)(ws + 32768);        // 663552 B
  __bf16* h1p = (__bf16*)(ws + (1 << 20));    // 79847424 B (padded NHWC)

  hipLaunchKernelGGL(stats_pass1, dim3(96), dim3(256), 0, stream, w1, w2, w3, pa);
  hipLaunchKernelGGL(stats2_pack_kernel, dim3(1440), dim3(256), 0, stream,
                     w1, w2, w3, pa, ps2, pc2, w1p, w2p, w3p);
  hipLaunchKernelGGL(conv1_kernel, dim3(112, 16), dim3(256), 0, stream, x, w1p,
                     g1, b1, m1, v1, ps2, pc2, g2, b2, m2, v2, g3, b3, m3, v3,
                     sc2, sh2, sc3, sh3, h1p);
  hipLaunchKernelGGL(conv2_kernel, dim3(56, 16), dim3(256), 0, stream, h1p, w2p, sc2, sh2,
                     w3p, sc3, sh3, x, out);
}

// Round 11
// 254.575 us; speedup vs baseline: 1.5801x; 1.0166x over previous
//
#include <hip/hip_runtime.h>

// ---------------------------------------------------------------------------
// TernaryInvertedResidual on MI355X (gfx950) — R15
//
// vs R14 (verified 258.8us; conv2=133.6us byte-stable): conv1 rebuilt as
// 2-row blocks (grid 56x16, 896 blocks — half of R14's 1792):
//   * w1p stage, alpha/BN-const compute, and staging setup amortized over
//     2 rows; x staged for both rows (smA 2x7168 | smB 12288, under the
//     57344 Pb union).
//   * both rows' bv frags + aw read into REGISTERS before the epilogue
//     reuses LDS as the P buffer (bv 2x7 + aw 3 ~ 68 regs; acc 84 regs,
//     rows processed sequentially -> ~170 VGPR, no cap on conv1).
//   * per-row epilogue/copyout/border identical values+destinations ->
//     bit-identical output.
// conv2_kernel byte-identical to verified R13/R14 (53760 B LDS, 3 blocks/CU,
// dbuf weights, gate-then-barrier, conv3-fused epilogue).
// stats1 / stats2_pack unchanged from verified R14.
// ---------------------------------------------------------------------------

typedef __bf16 bf16x8 __attribute__((ext_vector_type(8)));
typedef __bf16 bf16x4 __attribute__((ext_vector_type(4)));
typedef float  f32x4  __attribute__((ext_vector_type(4)));

#define EPSBN 1e-5f

// async global->LDS, 16B per lane; LDS dest = wave-uniform base + lane*16
__device__ __forceinline__ void glds16(const void* g, void* l) {
  __builtin_amdgcn_global_load_lds(
      (const __attribute__((address_space(1))) void*)g,
      (__attribute__((address_space(3))) void*)l, 16, 0, 0);
}

__device__ __forceinline__ __bf16 tern(float w, float delta) {
  float aw = fabsf(w);
  float q = (aw > delta) ? ((w > 0.0f) ? 1.0f : -1.0f) : 0.0f;
  return (__bf16)q;
}

// ---------------- stats pass 1 (abs-sum partials) --------------------------
// tensor index: 0=w1 (6144), 1=w2 (331776), 2=w3 (6144)
__global__ void stats_pass1(const float* __restrict__ w1, const float* __restrict__ w2,
                            const float* __restrict__ w3, double* __restrict__ pa) {
  __shared__ double red[256];
  int b = blockIdx.x, tid = threadIdx.x;
  int tix = b >> 5, slice = b & 31;
  const float* w = (tix == 0) ? w1 : (tix == 1) ? w2 : w3;
  int len = (tix == 1) ? 331776 : 6144;
  int per = len >> 5;
  int start = slice * per, end = start + per;
  double s = 0.0;
  for (int i = start + tid; i < end; i += 256) s += (double)fabsf(w[i]);
  red[tid] = s; __syncthreads();
  for (int off = 128; off > 0; off >>= 1) {
    if (tid < off) red[tid] += red[tid + off];
    __syncthreads();
  }
  if (tid == 0) pa[b] = red[0];
}

// ---------------- stats pass 2 + weight pack (merged, verified R14) --------
__global__ void stats2_pack_kernel(
    const float* __restrict__ w1, const float* __restrict__ w2, const float* __restrict__ w3,
    const double* __restrict__ pa, double* __restrict__ ps2, double* __restrict__ pc2,
    __bf16* __restrict__ w1p, __bf16* __restrict__ w2p, __bf16* __restrict__ w3p) {
  __shared__ double red[256];
  __shared__ float sdelta[3];
  int b = blockIdx.x, tid = threadIdx.x;

  if (b < 96) {   // ---- stats2, verbatim ----
    int tix = b >> 5, slice = b & 31;
    const float* w = (tix == 0) ? w1 : (tix == 1) ? w2 : w3;
    int len = (tix == 1) ? 331776 : 6144;
    double tot = 0.0;
    for (int k = 0; k < 32; ++k) tot += pa[tix * 32 + k];
    float delta = 0.7f * (float)(tot / (double)len);
    int per = len >> 5;
    int start = slice * per, end = start + per;
    double s2 = 0.0, c2 = 0.0;
    for (int i = start + tid; i < end; i += 256) {
      float aw = fabsf(w[i]);
      if (aw > delta) { s2 += (double)aw; c2 += 1.0; }
    }
    red[tid] = s2; __syncthreads();
    for (int off = 128; off > 0; off >>= 1) {
      if (tid < off) red[tid] += red[tid + off];
      __syncthreads();
    }
    if (tid == 0) ps2[b] = red[0];
    __syncthreads();
    red[tid] = c2; __syncthreads();
    for (int off = 128; off > 0; off >>= 1) {
      if (tid < off) red[tid] += red[tid + off];
      __syncthreads();
    }
    if (tid == 0) pc2[b] = red[0];
    return;
  }

  // ---- weight packing (delta-only; identical expressions) ----
  if (tid < 3) {
    double tot = 0.0;
    for (int k = 0; k < 32; ++k) tot += pa[tid * 32 + k];
    int len = (tid == 1) ? 331776 : 6144;
    sdelta[tid] = 0.7f * (float)(tot / (double)len);
  }
  __syncthreads();

  int idx = (b - 96) * 256 + tid;          // 0 .. 344063
  if (idx < 331776) {
    float delta2 = sdelta[1];
    int c = idx / 6144, rem = idx - c * 6144;
    int co = rem >> 5, r5 = rem & 31;
    int cp = r5 >> 3, lo = r5 & 7;
    int tap = c / 6, cb = c - tap * 6;
    int ci = ((cp ^ ((co >> 2) & 3)) << 3) | lo;   // source-side chunk swizzle
    int cifull = cb * 32 + ci;
    w2p[idx] = tern(w2[(co * 192 + cifull) * 9 + tap], delta2);
    return;
  }
  idx -= 331776;
  if (idx < 6144) {  // w1p, swizzled
    int co = idx >> 5, c = (idx >> 3) & 3, lo = idx & 7;
    int ci = ((c ^ ((co >> 2) & 3)) << 3) | lo;
    w1p[idx] = tern(w1[co * 32 + ci], sdelta[0]);
    return;
  }
  idx -= 6144;
  if (idx < 6144) {  // w3p, swizzled
    int kc = idx >> 11, rem = idx & 2047;
    int co = rem >> 6, c = (rem >> 3) & 7, lo = rem & 7;
    int ci = ((c ^ (co & 7)) << 3) | lo;
    w3p[idx] = tern(w3[co * 192 + kc * 64 + ci], sdelta[2]);
  }
}

// ---------------- conv1: 2-row blocks + BN-const production ----------------
// grid (56 h-pairs, 16 n), 256 threads (4 waves). Per-row math verbatim from
// verified R14 conv1; both rows' fragments register-resident before the
// Pb-union epilogue; rows processed sequentially through one P buffer.
__global__ __launch_bounds__(256)
void conv1_kernel(const float* __restrict__ x, const __bf16* __restrict__ w1p,
                  const float* __restrict__ g1, const float* __restrict__ b1,
                  const float* __restrict__ m1, const float* __restrict__ v1,
                  const double* __restrict__ ps2, const double* __restrict__ pc2,
                  const float* __restrict__ g2, const float* __restrict__ b2,
                  const float* __restrict__ m2, const float* __restrict__ v2,
                  const float* __restrict__ g3, const float* __restrict__ b3,
                  const float* __restrict__ m3, const float* __restrict__ v3,
                  float* __restrict__ sc2, float* __restrict__ sh2,
                  float* __restrict__ sc3, float* __restrict__ sh3,
                  __bf16* __restrict__ h1p) {
  __shared__ __align__(16) char smem[57344];
  __shared__ float salpha[3];
  __shared__ __align__(16) float sc1l[192];
  __shared__ __align__(16) float sh1l[192];
  char* smA = smem;           // 2 x 7168 B acts (rows r0,r1), chunk-swizzled
  char* smB = smem + 14336;   // 12288 B weights (swizzle baked in w1p)
  char* Pb  = smem;           // 57344 B epilogue union: 112 rows x 512 B
  int tid = threadIdx.x, lane = tid & 63, wave = tid >> 6;
  int bh = blockIdx.x, n = blockIdx.y;
  int h0 = bh * 2;

  for (int t = wave; t < 12; t += 4)
    glds16((const char*)w1p + t * 1024 + lane * 16, smB + t * 1024);

  // alphas (identical k-order) + BN1 consts into LDS
  if (tid < 3) {
    double s2 = 0.0, c2 = 0.0;
    for (int k = 0; k < 32; ++k) {
      s2 += ps2[tid * 32 + k];
      c2 += pc2[tid * 32 + k];
    }
    salpha[tid] = (float)(s2 / fmax(c2, 1.0));
  }
  __syncthreads();
  if (tid < 192) {
    float rs = rsqrtf(v1[tid] + EPSBN);
    sc1l[tid] = g1[tid] * rs * salpha[0];
    sh1l[tid] = b1[tid] - m1[tid] * g1[tid] * rs;
  }
  // block (0,0): produce conv2/conv3 BN consts (stream order covers conv2)
  if (bh == 0 && n == 0) {
    if (tid < 192) {
      float rs = rsqrtf(v2[tid] + EPSBN);
      sc2[tid] = g2[tid] * rs * salpha[1];
      sh2[tid] = b2[tid] - m2[tid] * g2[tid] * rs;
    } else if (tid < 224) {
      int j = tid - 192;
      float rs = rsqrtf(v3[j] + EPSBN);
      sc3[j] = g3[j] * rs * salpha[2];
      sh3[j] = b3[j] - m3[j] * g3[j] * rs;
    }
  }

  // x staging for both rows: identical per-row scheme to verified R14
  const float* xn = x + (long)n * 401408;   // + ci*12544 + h*112 + w
#pragma unroll
  for (int i = 0; i < 7; ++i) {
    int g = i * 256 + tid;
    if (g < 1792) {
      int r = g >> 10 ? 1 : (g >= 896 ? 1 : 0);   // r = g/896
      int gg = g - r * 896;
      int ci0 = (gg / 112) * 4, w = gg - (gg / 112) * 112;
      const float* p = xn + ci0 * 12544 + (h0 + r) * 112 + w;
      bf16x4 v;
      v[0] = (__bf16)p[0];
      v[1] = (__bf16)p[12544];
      v[2] = (__bf16)p[25088];
      v[3] = (__bf16)p[37632];
      int col = ((ci0 >> 3) ^ ((w >> 2) & 3));
      *(bf16x4*)(smA + r * 7168 + w * 64 + (col << 4) + (ci0 & 7) * 2) = v;
    }
  }
  __syncthreads();

  int mrow = lane & 15, quad = lane >> 4;
  int col16 = (quad ^ ((mrow >> 2) & 3)) * 16;
  int c0 = wave * 48;

  // read ALL fragments (weights + both rows' acts) into registers
  bf16x8 aw[3], bv0[7], bv1[7];
#pragma unroll
  for (int ic = 0; ic < 3; ++ic)
    aw[ic] = *(const bf16x8*)(smB + (c0 + ic * 16 + mrow) * 64 + col16);
#pragma unroll
  for (int jp = 0; jp < 7; ++jp) {
    bv0[jp] = *(const bf16x8*)(smA + (jp * 16 + mrow) * 64 + col16);
    bv1[jp] = *(const bf16x8*)(smA + 7168 + (jp * 16 + mrow) * 64 + col16);
  }

  // frags in flight; drain + fence before LDS is reused as P buffer
  asm volatile("s_waitcnt lgkmcnt(0)" ::: "memory");
  __builtin_amdgcn_s_barrier();
  __builtin_amdgcn_sched_barrier(0);

#pragma unroll
  for (int r = 0; r < 2; ++r) {
    int h = h0 + r;

    f32x4 acc[7][3];
#pragma unroll
    for (int jp = 0; jp < 7; ++jp)
#pragma unroll
      for (int ic = 0; ic < 3; ++ic) acc[jp][ic] = (f32x4)0.0f;

#pragma unroll
    for (int jp = 0; jp < 7; ++jp)
#pragma unroll
      for (int ic = 0; ic < 3; ++ic)
        acc[jp][ic] = __builtin_amdgcn_mfma_f32_16x16x32_bf16(
            aw[ic], (r == 0) ? bv0[jp] : bv1[jp], acc[jp][ic], 0, 0, 0);

    // epilogue: BN + ReLU6 -> P LDS (padded 512B rows, chunk XOR (w&31))
#pragma unroll
    for (int ic = 0; ic < 3; ++ic) {
      int co0 = c0 + ic * 16 + quad * 4;
      float4 sc = *(const float4*)(sc1l + co0);
      float4 sh = *(const float4*)(sh1l + co0);
      int lch = co0 >> 3;                 // 6*wave + 2*ic + (quad>>1)
      int boff = (quad & 1) * 8;          // (co0&7)*2
#pragma unroll
      for (int jp = 0; jp < 7; ++jp) {
        int w = jp * 16 + mrow;
        bf16x4 o;
        o[0] = (__bf16)fminf(fmaxf(acc[jp][ic][0] * sc.x + sh.x, 0.0f), 6.0f);
        o[1] = (__bf16)fminf(fmaxf(acc[jp][ic][1] * sc.y + sh.y, 0.0f), 6.0f);
        o[2] = (__bf16)fminf(fmaxf(acc[jp][ic][2] * sc.z + sh.z, 0.0f), 6.0f);
        o[3] = (__bf16)fminf(fmaxf(acc[jp][ic][3] * sc.w + sh.w, 0.0f), 6.0f);
        *(bf16x4*)(Pb + w * 512 + ((lch ^ (w & 31)) << 4) + boff) = o;
      }
    }
    asm volatile("s_waitcnt lgkmcnt(0)" ::: "memory");
    __builtin_amdgcn_s_barrier();
    __builtin_amdgcn_sched_barrier(0);

    // coalesced copy-out: interior row = contiguous 2688 x 16B
    __bf16* obase = h1p + ((long)(n * 114 + h + 1) * 114 + 1) * 192;
#pragma unroll
    for (int i = 0; i < 11; ++i) {
      int c = i * 256 + tid;
      if (c < 2688) {
        int w = c / 24, lch = c - w * 24;
        float4 v = *(const float4*)(Pb + w * 512 + ((lch ^ (w & 31)) << 4));
        *(float4*)((char*)obase + c * 16) = v;
      }
    }

    // fused border zeroing for this row (+ top/bottom full rows)
    float4 z = make_float4(0.f, 0.f, 0.f, 0.f);
    if (tid < 48) {
      int px = (tid < 24) ? 0 : 113;
      int c8 = (tid < 24) ? tid : tid - 24;
      *(float4*)((char*)h1p + ((long)((n * 114 + h + 1) * 114 + px) * 384) + c8 * 16) = z;
    }
    if (h == 0) {
      for (int c = tid; c < 2736; c += 256)
        *(float4*)((char*)h1p + (long)(n * 114) * 114 * 384 + c * 16) = z;
    }
    if (h == 111) {
      for (int c = tid; c < 2736; c += 256)
        *(float4*)((char*)h1p + (long)(n * 114 + 113) * 114 * 384 + c * 16) = z;
    }

    if (r == 0) {   // Pb reads consumed before row 1 overwrites it
      asm volatile("s_waitcnt lgkmcnt(0)" ::: "memory");
      __builtin_amdgcn_s_barrier();
      __builtin_amdgcn_sched_barrier(0);
    }
  }
}

// ---------------- conv2+conv3 fused (byte-identical to verified R13/R14) ---
#define STAGE_W(TAP, CB, B) do {                                              \
  _Pragma("unroll")                                                           \
  for (int it_ = 0; it_ < 3; ++it_) {                                         \
    int t_ = wave + it_ * 4;                                                  \
    glds16(w2b + (long)((TAP) * 6 + (CB)) * 12288 + t_ * 1024 + lane * 16,    \
           smBb + (B) * 12288 + t_ * 1024);                                   \
  }                                                                           \
} while (0)

#define STAGE_A(CB) do {                                                      \
  _Pragma("unroll")                                                           \
  for (int it_ = 0; it_ < 8; ++it_)                                           \
    if (aoff[it_] >= 0)                                                       \
      glds16(h1b + aoff[it_] + (CB) * 64, smAb + (wave + it_ * 4) * 1024);    \
} while (0)

__global__ __launch_bounds__(256, 2)
void conv2_kernel(const __bf16* __restrict__ h1p, const __bf16* __restrict__ w2p,
                  const float* __restrict__ scale2, const float* __restrict__ shift2,
                  const __bf16* __restrict__ w3p,
                  const float* __restrict__ scale3, const float* __restrict__ shift3,
                  const float* __restrict__ x, float* __restrict__ out) {
  __shared__ __align__(16) char smem[53760];
  char* smAb = smem;            // 29184 B act window (main loop)
  char* smBb = smem + 29184;    // 2 x 12288 B weights, double-buffered
  char* Pb   = smem;            // 43008 B P-row (epilogue union)
  int tid = threadIdx.x, lane = tid & 63, wave = tid >> 6;
  int bh = blockIdx.x, n = blockIdx.y;
  int h0 = bh * 2;

  // A staging source offsets (bytes, + cb*64 at use); slot s = t*64+lane
  int aoff[8];
#pragma unroll
  for (int it = 0; it < 8; ++it) {
    int t = wave + it * 4;
    int s = t * 64 + lane;
    if (s < 1824) {
      int q = s >> 2, c = s & 3;
      int q_log = c ^ ((q >> 2) & 3);
      int prow = q / 114, pcol = q - prow * 114;
      aoff[it] = ((n * 114 + h0 + prow) * 114 + pcol) * 384 + q_log * 16;
    } else {
      aoff[it] = -1;
    }
  }

  int pg = wave >> 1, cg = wave & 1;
  int mrow = lane & 15, quad = lane >> 4;
  int col16 = (quad ^ ((mrow >> 2) & 3)) * 16;
  const char* h1b = (const char*)h1p;
  const char* w2b = (const char*)w2p;

  f32x4 acc[7][6];
#pragma unroll
  for (int jp = 0; jp < 7; ++jp)
#pragma unroll
    for (int ic = 0; ic < 6; ++ic) acc[jp][ic] = (f32x4)0.0f;

  // prologue: A(0) + W0->buf0 in flight before the first tap
  STAGE_A(0);
  STAGE_W(0, 0, 0);

  for (int cb = 0; cb < 6; ++cb) {
#pragma unroll
    for (int tap = 0; tap < 9; ++tap) {
      // gate own loads BEFORE the barrier (R8 pattern) -> block-wide visible
      asm volatile("s_waitcnt vmcnt(0)" ::: "memory");
      __builtin_amdgcn_s_barrier();
      __builtin_amdgcn_sched_barrier(0);
      if (tap <= 7)
        STAGE_W(tap + 1, cb, (tap + 1) & 1);   // buf last read at tap-1: idle

      const char* bbuf = smBb + (tap & 1) * 12288;
      bf16x8 aw[6];
#pragma unroll
      for (int ic = 0; ic < 6; ++ic)
        aw[ic] = *(const bf16x8*)(bbuf + (cg * 96 + ic * 16 + mrow) * 64 + col16);

      int dy = tap / 3, dx = tap - dy * 3;
      int base = (pg + dy) * 114 + dx;
      __builtin_amdgcn_s_setprio(1);
#pragma unroll
      for (int jp = 0; jp < 7; ++jp) {
        int row = base + jp * 16 + mrow;
        bf16x8 av = *(const bf16x8*)(smAb + row * 64 +
                                     ((quad ^ ((row >> 2) & 3)) * 16));
#pragma unroll
        for (int ic = 0; ic < 6; ++ic)
          acc[jp][ic] = __builtin_amdgcn_mfma_f32_16x16x32_bf16(aw[ic], av, acc[jp][ic], 0, 0, 0);
      }
      __builtin_amdgcn_s_setprio(0);
    }

    // seam: all waves issued tap-8 MFMAs at this barrier -> smA reads done
    if (cb < 5) {
      __builtin_amdgcn_s_barrier();
      __builtin_amdgcn_sched_barrier(0);
      STAGE_A(cb + 1);
      STAGE_W(0, cb + 1, 0);
    }
  }

  // ---------------- fused conv3 epilogue ----------------------------------
  asm volatile("s_waitcnt lgkmcnt(0)" ::: "memory");
  __builtin_amdgcn_s_barrier();
  __builtin_amdgcn_sched_barrier(0);

  // per-lane conv3 BN params: co = (wave&1)*16 + mrow
  int cohalf = wave & 1;
  int co3 = cohalf * 16 + mrow;
  float sc3v = scale3[co3], sh3v = shift3[co3];
  int fbase = (wave >> 1) * 4;             // waves 0,1 -> frags 0..3; 2,3 -> 4..6
  int swz = mrow & 7;

  // w3 b-fragments straight from global (same bits as the old LDS stage)
  bf16x8 wb0[3], wb1[3];
#pragma unroll
  for (int kc = 0; kc < 3; ++kc) {
    wb0[kc] = *(const bf16x8*)((const char*)w3p + kc * 4096 +
                               (cohalf * 16 + mrow) * 128 + ((quad ^ swz) * 16));
    wb1[kc] = *(const bf16x8*)((const char*)w3p + kc * 4096 +
                               (cohalf * 16 + mrow) * 128 + (((4 + quad) ^ swz) * 16));
  }

#pragma unroll
  for (int rg = 0; rg < 2; ++rg) {
    if (pg == rg) {
      // write this wave's half (cg) of P-row rg
#pragma unroll
      for (int ic = 0; ic < 6; ++ic) {
        int co0 = cg * 96 + ic * 16 + quad * 4;
        float4 sc = *(const float4*)(scale2 + co0);
        float4 sh = *(const float4*)(shift2 + co0);
        int kc = co0 >> 6, c6 = co0 & 63;
        int chunk = c6 >> 3, off = c6 & 7;
#pragma unroll
        for (int jp = 0; jp < 7; ++jp) {
          int px = jp * 16 + mrow;
          bf16x4 o;
          o[0] = (__bf16)fminf(fmaxf(acc[jp][ic][0] * sc.x + sh.x, 0.0f), 6.0f);
          o[1] = (__bf16)fminf(fmaxf(acc[jp][ic][1] * sc.y + sh.y, 0.0f), 6.0f);
          o[2] = (__bf16)fminf(fmaxf(acc[jp][ic][2] * sc.z + sh.z, 0.0f), 6.0f);
          o[3] = (__bf16)fminf(fmaxf(acc[jp][ic][3] * sc.w + sh.w, 0.0f), 6.0f);
          *(bf16x4*)(Pb + px * 384 + kc * 128 + ((chunk ^ (px & 7)) * 16) + off * 2) = o;
        }
      }
    }
    asm volatile("s_waitcnt lgkmcnt(0)" ::: "memory");
    __builtin_amdgcn_s_barrier();
    __builtin_amdgcn_sched_barrier(0);

    // conv3 on row rg: wave covers co 16*(wave&1).. and px frags fbase..(+3|+2)
    f32x4 acc3[4];
#pragma unroll
    for (int f = 0; f < 4; ++f) acc3[f] = (f32x4)0.0f;
#pragma unroll
    for (int kc = 0; kc < 3; ++kc) {
#pragma unroll
      for (int f = 0; f < 4; ++f) {
        if (fbase + f < 7) {
          int pr = (fbase + f) * 16 + mrow;
          bf16x8 a0 = *(const bf16x8*)(Pb + pr * 384 + kc * 128 + ((quad ^ swz) * 16));
          bf16x8 a1 = *(const bf16x8*)(Pb + pr * 384 + kc * 128 + (((4 + quad) ^ swz) * 16));
          acc3[f] = __builtin_amdgcn_mfma_f32_16x16x32_bf16(a0, wb0[kc], acc3[f], 0, 0, 0);
          acc3[f] = __builtin_amdgcn_mfma_f32_16x16x32_bf16(a1, wb1[kc], acc3[f], 0, 0, 0);
        }
      }
    }
    // BN (no act) + residual, fp32 float4 stores to NCHW
    int h = h0 + rg;
    long obase = ((long)(n * 32 + co3) * 112 + h) * 112;
    const float* xb = x + obase;
    float* ob = out + obase;
#pragma unroll
    for (int f = 0; f < 4; ++f) {
      if (fbase + f < 7) {
        int w0 = (fbase + f) * 16 + quad * 4;
        float4 xv = *(const float4*)(xb + w0);
        float4 o;
        o.x = acc3[f][0] * sc3v + sh3v + xv.x;
        o.y = acc3[f][1] * sc3v + sh3v + xv.y;
        o.z = acc3[f][2] * sc3v + sh3v + xv.z;
        o.w = acc3[f][3] * sc3v + sh3v + xv.w;
        *(float4*)(ob + w0) = o;
      }
    }
    if (rg == 0) {
      asm volatile("s_waitcnt lgkmcnt(0)" ::: "memory");
      __builtin_amdgcn_s_barrier();
      __builtin_amdgcn_sched_barrier(0);
    }
  }
}

// ---------------- launch ---------------------------------------------------
extern "C" void kernel_launch(void* const* d_in, const int* in_sizes, int n_in,
                              void* d_out, int out_size, void* d_ws, size_t ws_size,
                              hipStream_t stream) {
  const float* x  = (const float*)d_in[0];
  const float* w1 = (const float*)d_in[1];
  const float* g1 = (const float*)d_in[2];
  const float* b1 = (const float*)d_in[3];
  const float* m1 = (const float*)d_in[4];
  const float* v1 = (const float*)d_in[5];
  const float* w2 = (const float*)d_in[6];
  const float* g2 = (const float*)d_in[7];
  const float* b2 = (const float*)d_in[8];
  const float* m2 = (const float*)d_in[9];
  const float* v2 = (const float*)d_in[10];
  const float* w3 = (const float*)d_in[11];
  const float* g3 = (const float*)d_in[12];
  const float* b3 = (const float*)d_in[13];
  const float* m3 = (const float*)d_in[14];
  const float* v3 = (const float*)d_in[15];
  float* out = (float*)d_out;

  char* ws = (char*)d_ws;
  double* pa    = (double*)(ws + 256);        // 96 doubles
  double* ps2   = (double*)(ws + 1024);
  double* pc2   = (double*)(ws + 1792);
  float* sc2 = (float*)(ws + 4096);
  float* sh2 = (float*)(ws + 4864);
  float* sc3 = (float*)(ws + 5632);
  float* sh3 = (float*)(ws + 5760);
  __bf16* w1p = (__bf16*)(ws + 8192);         // 12288 B
  __bf16* w3p = (__bf16*)(ws + 20480);        // 12288 B
  __bf16* w2p = (__bf16*)(ws + 32768);        // 663552 B
  __bf16* h1p = (__bf16*)(ws + (1 << 20));    // 79847424 B (padded NHWC)

  hipLaunchKernelGGL(stats_pass1, dim3(96), dim3(256), 0, stream, w1, w2, w3, pa);
  hipLaunchKernelGGL(stats2_pack_kernel, dim3(1440), dim3(256), 0, stream,
                     w1, w2, w3, pa, ps2, pc2, w1p, w2p, w3p);
  hipLaunchKernelGGL(conv1_kernel, dim3(56, 16), dim3(256), 0, stream, x, w1p,
                     g1, b1, m1, v1, ps2, pc2, g2, b2, m2, v2, g3, b3, m3, v3,
                     sc2, sh2, sc3, sh3, h1p);
  hipLaunchKernelGGL(conv2_kernel, dim3(56, 16), dim3(256), 0, stream, h1p, w2p, sc2, sh2,
                     w3p, sc3, sh3, x, out);
}